// Round 14
// baseline (740.847 us; speedup 1.0000x reference)
//
#include <hip/hip_runtime.h>
#include <hip/hip_bf16.h>

// Problem constants: D=1024, N=4096, K=16, M = N*K = 65536, K-dim main = 2048

typedef __attribute__((ext_vector_type(4))) float f32x4;
typedef __attribute__((ext_vector_type(2))) float f32x2;
typedef __attribute__((ext_vector_type(8))) short bf16x8;

__device__ __forceinline__ ushort f2bf(float f) {
  unsigned b = __builtin_bit_cast(unsigned, f);
  b += 0x7FFFu + ((b >> 16) & 1u);   // RNE
  return (ushort)(b >> 16);
}
__device__ __forceinline__ unsigned pk2(float a, float b) {
  return (unsigned)f2bf(a) | ((unsigned)f2bf(b) << 16);
}

// LDS XOR swizzle for the A tile (verified R1/R4/R6-R13). Keyed on byte addr
// bits 7,8 = row bits 1,2 for 64B rows — identical pattern for the 2KB
// [32][32]bf16 tile (rows still 64B).
__device__ __forceinline__ unsigned swz(unsigned a) {
  return a ^ (((a >> 7) & 3u) << 4);
}

__device__ __forceinline__ bf16x8 cvt8(const float* p) {
  f32x4 a = *(const f32x4*)p;
  f32x4 b = *(const f32x4*)(p + 4);
  bf16x8 r;
  r[0] = (short)f2bf(a[0]); r[1] = (short)f2bf(a[1]);
  r[2] = (short)f2bf(a[2]); r[3] = (short)f2bf(a[3]);
  r[4] = (short)f2bf(b[0]); r[5] = (short)f2bf(b[1]);
  r[6] = (short)f2bf(b[2]); r[7] = (short)f2bf(b[3]);
  return r;
}

// Non-temporal variants for read-once streams (R13: +8% win, keep).
__device__ __forceinline__ bf16x8 cvt8nt(const float* p) {
  f32x4 a = __builtin_nontemporal_load((const f32x4*)p);
  f32x4 b = __builtin_nontemporal_load((const f32x4*)(p + 4));
  bf16x8 r;
  r[0] = (short)f2bf(a[0]); r[1] = (short)f2bf(a[1]);
  r[2] = (short)f2bf(a[2]); r[3] = (short)f2bf(a[3]);
  r[4] = (short)f2bf(b[0]); r[5] = (short)f2bf(b[1]);
  r[6] = (short)f2bf(b[2]); r[7] = (short)f2bf(b[3]);
  return r;
}
__device__ __forceinline__ f32x2 ntld2(const float* p) {
  return __builtin_nontemporal_load((const f32x2*)p);
}

// ---------------------------------------------------------------------------
// prep: LDS tile-transpose weight packer (verified green R4-R13).
// mode 0 (bid<512):  Bmain packed layout: flat = kt*32768 + wg*4096 + c*8 + m,
//                    chunk c = nf*64 + lane; value = Wl[1024+kt*32+(lane>>4)*8+m]
//                                                      [wg*128+nf*16+(lane&15)]
// mode 1 (512..768): Bk1 layout [kt][nn][q*8+m] from Wl rows 0..1023
// mode 2 (768..1280): Bgate same layout from Wg rows kt*32 (+ row+1024 summed
//                    when kt>=32)
// ---------------------------------------------------------------------------
__global__ __launch_bounds__(256) void prep_kernel(
    const float* __restrict__ Wl, const float* __restrict__ Wg,
    ushort* __restrict__ Bmain, ushort* __restrict__ Bk1,
    ushort* __restrict__ Bgate) {
  __shared__ float L[32][129];
  int t = threadIdx.x;
  int bid = blockIdx.x;
  const float* src; int row0, mode, kt, wg; ushort* dst;
  if (bid < 512)      { mode = 0; kt = bid >> 3;        wg = bid & 7; src = Wl; row0 = 1024 + kt * 32; dst = Bmain; }
  else if (bid < 768) { mode = 1; kt = (bid - 512) >> 3; wg = (bid - 512) & 7; src = Wl; row0 = kt * 32; dst = Bk1; }
  else                { mode = 2; kt = (bid - 768) >> 3; wg = (bid - 768) & 7; src = Wg; row0 = kt * 32; dst = Bgate; }
  int col0 = wg * 128;
  bool dosum = (mode == 2) && (kt >= 32);
#pragma unroll
  for (int p = 0; p < 4; ++p) {
    int r = p * 8 + (t >> 5), c = (t & 31) * 4;
    const float* sp = src + (size_t)(row0 + r) * 1024 + col0 + c;
    f32x4 v = *(const f32x4*)sp;
    if (dosum) { f32x4 v2 = *(const f32x4*)(sp + (size_t)1024 * 1024); v += v2; }
    L[r][c] = v[0]; L[r][c + 1] = v[1]; L[r][c + 2] = v[2]; L[r][c + 3] = v[3];
  }
  __syncthreads();
  if (mode == 0) {
    for (int c = t; c < 512; c += 256) {
      int nf = c >> 6, lane = c & 63, lr_ = lane & 15, lh_ = lane >> 4;
      bf16x8 o;
#pragma unroll
      for (int m = 0; m < 8; ++m) o[m] = (short)f2bf(L[lh_ * 8 + m][nf * 16 + lr_]);
      *(bf16x8*)(dst + (size_t)kt * 32768 + wg * 4096 + c * 8) = o;
    }
  } else {
    for (int c = t; c < 512; c += 256) {
      int nn = c >> 2, q = c & 3;
      bf16x8 o;
#pragma unroll
      for (int m = 0; m < 8; ++m) o[m] = (short)f2bf(L[q * 8 + m][nn]);
      *(bf16x8*)(dst + (size_t)kt * 32768 + (size_t)(wg * 128 + nn) * 32 + q * 8) = o;
    }
  }
}

// ---------------------------------------------------------------------------
// gemm_small: C = act(A_f32 @ Bpack + bias). 64x128 tile, 4 waves (2x2),
// wave tile 32x64. grid (M/64, 8) = 512 blocks -> 2 blocks/CU. (green)
// ---------------------------------------------------------------------------
template <int NKT, int NSPLIT, int ACT>
__global__ __launch_bounds__(256) void gemm_small(
    const float* __restrict__ A0, const float* __restrict__ A1,
    const ushort* __restrict__ Bp, const float* __restrict__ bias,
    float* __restrict__ Cout) {
  int tid = threadIdx.x, l = tid & 63, wid = tid >> 6;
  int wm = wid & 1, wn = wid >> 1;
  int mbase = blockIdx.x * 64 + wm * 32;
  int nbase = blockIdx.y * 128 + wn * 64;
  int lr = l & 15, lh = l >> 4;
  f32x4 acc[2][4] = {};
#pragma unroll 1
  for (int kt = 0; kt < NKT; ++kt) {
    const float* As = (kt < NSPLIT) ? A0 : A1;
    int ke = ((kt < NSPLIT) ? kt : kt - NSPLIT) * 32 + lh * 8;
    bf16x8 af[2];
#pragma unroll
    for (int mf = 0; mf < 2; ++mf)
      af[mf] = cvt8nt(As + (size_t)(mbase + mf * 16 + lr) * 1024 + ke);
    bf16x8 bf[4];
#pragma unroll
    for (int nf = 0; nf < 4; ++nf)
      bf[nf] = *(const bf16x8*)(Bp + (size_t)kt * 32768 +
                                (size_t)(nbase + nf * 16 + lr) * 32 + lh * 8);
#pragma unroll
    for (int nf = 0; nf < 4; ++nf)
#pragma unroll
      for (int mf = 0; mf < 2; ++mf)
        acc[mf][nf] = __builtin_amdgcn_mfma_f32_16x16x32_bf16(
            af[mf], bf[nf], acc[mf][nf], 0, 0, 0);
  }
#pragma unroll
  for (int nf = 0; nf < 4; ++nf) {
    int col = nbase + nf * 16 + lr;
    float bs = bias[col];
#pragma unroll
    for (int mf = 0; mf < 2; ++mf)
#pragma unroll
      for (int j = 0; j < 4; ++j) {
        int row = mbase + mf * 16 + lh * 4 + j;
        float v = acc[mf][nf][j] + bs;
        if (ACT == 1) v = 1.0f / (1.0f + expf(-v));
        Cout[(size_t)row * 1024 + col] = v;
      }
  }
}

// ---------------------------------------------------------------------------
// main fused kernel — 2 CO-RESIDENT BLOCKS PER CU. R4-R13 all ran exactly
// 1 block/CU (64-row tile => acc 64 AGPR + ~64 VGPR = 128 regs x 16 waves);
// the issue port measured only 37% busy and no intra-block schedule moved it.
// m97's 874TF credits ~3 co-resident blocks ("implicit wave-level overlap")
// for absorbing barrier/latency stalls. This kernel: 32-row x 1024-col block,
// 8 waves (512 thr), wave tile 32x128, acc[2][8]=64 AGPR + ~50 VGPR ->
// __launch_bounds__(512,4) -> 16 waves/CU = TWO independent blocks whose
// barriers anti-phase. B single-buffered (reg budget; exposed ~250cy L2
// latency absorbed by the other block). B L2 traffic doubles (accepted).
// A: f32 -> reg -> bf16 -> swizzled 2KB LDS tile, dbuf, 1-step-ahead (NT).
// Epilogue: +t_part, exact GELU, LayerNorm (8-wave LDS reduce over 32 rows),
// softmax-weighted K-reduce (2 tokens/block) -> arg_summary.
// ---------------------------------------------------------------------------
#define MFMA_STEP(ABSYM, BF) do {                                         \
  const char* ab_ = (const char*)(ABSYM) + aoff0;                         \
  bf16x8 af_[2];                                                          \
  _Pragma("unroll")                                                       \
  for (int mf = 0; mf < 2; ++mf)                                          \
    af_[mf] = *(const bf16x8*)(ab_ + mf * 1024);                          \
  _Pragma("unroll")                                                       \
  for (int nf = 0; nf < 8; ++nf)                                          \
    _Pragma("unroll")                                                     \
    for (int mf = 0; mf < 2; ++mf)                                        \
      acc[mf][nf] = __builtin_amdgcn_mfma_f32_16x16x32_bf16(              \
          af_[mf], (BF)[nf], acc[mf][nf], 0, 0, 0);                       \
} while (0)

// Raw barrier: LDS ordering only; VGPR-dest global loads stay in flight.
#define BARRIER_LG() do {                                                 \
  asm volatile("s_waitcnt lgkmcnt(0)" ::: "memory");                      \
  __builtin_amdgcn_s_barrier();                                           \
  asm volatile("" ::: "memory");                                          \
} while (0)

__global__ __launch_bounds__(512, 4) void main_kernel(
    const float* __restrict__ routed, const float* __restrict__ delta,
    const float* __restrict__ simrow, const ushort* __restrict__ Bmain,
    const float* __restrict__ tpart, const float* __restrict__ gamma,
    const float* __restrict__ beta, float* __restrict__ out_arg) {
  __shared__ ushort Ab0[1024];          // 2KB A tile [32][32] bf16 (swz)
  __shared__ ushort Ab1[1024];
  __shared__ float ldsW[32];            // softmax weights 2 tokens x 16 k
  __shared__ float lnS[32 * 8], lnQ[32 * 8];

  int tid = threadIdx.x, l = tid & 63, wid = tid >> 6;   // wid 0..7
  int bx = blockIdx.x;                  // tokens bx*2, bx*2+1
  int lr = l & 15, lh = l >> 4;

  if (tid < 2) {                        // softmax over K=16 for token bx*2+tid
    int n = bx * 2 + tid;
    float sv[16], mx = -1e30f;
#pragma unroll
    for (int j = 0; j < 16; ++j) { sv[j] = simrow[n * 16 + j]; mx = fmaxf(mx, sv[j]); }
    float s = 0.f;
#pragma unroll
    for (int j = 0; j < 16; ++j) { sv[j] = expf(sv[j] - mx); s += sv[j]; }
    float inv = 1.0f / s;
#pragma unroll
    for (int j = 0; j < 16; ++j) ldsW[tid * 16 + j] = sv[j] * inv;
  }

  // A staging geometry: 512 threads x 8B f32 read -> 4B bf16 write of the
  // 2KB tile. thread -> row tid>>4 (0..31), f32 col pair (tid&15)*2.
  const float* rbase = routed + (size_t)(bx * 32 + (tid >> 4)) * 1024 + (tid & 15) * 2;
  const float* dbase = delta  + (size_t)(bx * 32 + (tid >> 4)) * 1024 + (tid & 15) * 2;
  const unsigned adst = swz((unsigned)tid * 4);

  // A-tile read base (swz XOR independent of mf: +16 rows = +1024B leaves
  // addr bits 7,8 = row bits 1,2 unchanged)
  const unsigned aoff0 = swz((unsigned)lr * 64 + (unsigned)lh * 16);

  // B per-lane pointer: wave wid covers cols wid*128 + nf*16 + lr.
  // packed layout: wg == wid, chunk = nf*64 + l -> 16B/lane coalesced.
  const ushort* bptr = Bmain + (size_t)wid * 4096 + (size_t)l * 8;

  // ---- prologue: A(0)->Ab0, A(1)->avA ----
  f32x2 t0 = ntld2(rbase);
  f32x2 avA = ntld2(rbase + 32);
  f32x2 avB;
  *(unsigned*)((char*)Ab0 + adst) = pk2(t0[0], t0[1]);
  BARRIER_LG();

  f32x4 acc[2][8] = {};
#pragma unroll 1
  for (int kt = 0; kt < 64; kt += 2) {
    // ===== even step: consume Ab0 + B(kt) =====
    {                                    // A(kt+2) issued, stays in flight
      const float* as_ = (kt + 2 < 32) ? rbase : dbase;
      avB = ntld2(as_ + (size_t)((kt + 2) & 31) * 32);
    }
    {
      bf16x8 bf[8];
#pragma unroll
      for (int nf = 0; nf < 8; ++nf)
        bf[nf] = *(const bf16x8*)(bptr + (size_t)kt * 32768 + nf * 512);
      MFMA_STEP(Ab0, bf);
    }
    *(unsigned*)((char*)Ab1 + adst) = pk2(avA[0], avA[1]);   // A(kt+1)->Ab1
    BARRIER_LG();
    // ===== odd step: consume Ab1 + B(kt+1) =====
    {                                    // A(kt+3) (benign over-read at end)
      const float* as_ = (kt + 3 < 32) ? rbase : dbase;
      avA = ntld2(as_ + (size_t)((kt + 3) & 31) * 32);
    }
    {
      bf16x8 bf[8];
#pragma unroll
      for (int nf = 0; nf < 8; ++nf)
        bf[nf] = *(const bf16x8*)(bptr + (size_t)(kt + 1) * 32768 + nf * 512);
      MFMA_STEP(Ab1, bf);
    }
    *(unsigned*)((char*)Ab0 + adst) = pk2(avB[0], avB[1]);   // A(kt+2)->Ab0
    BARRIER_LG();
  }

  // ---- fused epilogue ----
  // acc[mf][nf][j]: local row mf*16 + lh*4 + j (= token mf, k = lh*4+j),
  //                 col wid*128 + nf*16 + lr
  const float inv_d = 1.0f / 1024.0f;
  float gam[8], bet[8];
#pragma unroll
  for (int nf = 0; nf < 8; ++nf) {
    int c = wid * 128 + nf * 16 + lr;
    gam[nf] = gamma[c]; bet[nf] = beta[c];
  }
#pragma unroll
  for (int mf = 0; mf < 2; ++mf) {
    int tokrow = bx * 2 + mf;
    float s[4] = {0, 0, 0, 0}, q[4] = {0, 0, 0, 0};
#pragma unroll
    for (int nf = 0; nf < 8; ++nf) {
      float tp = __builtin_nontemporal_load(
          tpart + (size_t)tokrow * 1024 + wid * 128 + nf * 16 + lr);
#pragma unroll
      for (int j = 0; j < 4; ++j) {
        float h = acc[mf][nf][j] + tp;
        float g = 0.5f * h * (1.0f + erff(h * 0.70710678118654752f));
        acc[mf][nf][j] = g;
        s[j] += g; q[j] += g * g;
      }
    }
#pragma unroll
    for (int j = 0; j < 4; ++j) {
#pragma unroll
      for (int d = 1; d <= 8; d <<= 1) {
        s[j] += __shfl_xor(s[j], d, 64);
        q[j] += __shfl_xor(q[j], d, 64);
      }
    }
    if (lr == 0) {
#pragma unroll
      for (int j = 0; j < 4; ++j) {
        int row = mf * 16 + lh * 4 + j;
        lnS[row * 8 + wid] = s[j];
        lnQ[row * 8 + wid] = q[j];
      }
    }
  }
  __syncthreads();
#pragma unroll
  for (int mf = 0; mf < 2; ++mf) {
    float mu[4], rs[4], wk[4];
#pragma unroll
    for (int j = 0; j < 4; ++j) {
      int row = mf * 16 + lh * 4 + j;
      float S = 0.f, Q = 0.f;
#pragma unroll
      for (int w4 = 0; w4 < 2; ++w4) {
        f32x4 vs = *(const f32x4*)&lnS[row * 8 + w4 * 4];
        f32x4 vq = *(const f32x4*)&lnQ[row * 8 + w4 * 4];
        S += vs[0] + vs[1] + vs[2] + vs[3];
        Q += vq[0] + vq[1] + vq[2] + vq[3];
      }
      float m_ = S * inv_d;
      mu[j] = m_;
      rs[j] = rsqrtf(Q * inv_d - m_ * m_ + 1e-5f);
      wk[j] = ldsW[row];
    }
#pragma unroll
    for (int nf = 0; nf < 8; ++nf) {
      float ws = 0.f;
#pragma unroll
      for (int j = 0; j < 4; ++j) {
        float y = (acc[mf][nf][j] - mu[j]) * rs[j] * gam[nf] + bet[nf];
        ws += wk[j] * y;
      }
      ws += __shfl_xor(ws, 16, 64);
      ws += __shfl_xor(ws, 32, 64);
      if (lh == 0)
        out_arg[(size_t)(bx * 2 + mf) * 1024 + wid * 128 + nf * 16 + lr] = ws;
    }
  }
}

// ---------------------------------------------------------------------------
extern "C" void kernel_launch(void* const* d_in, const int* in_sizes, int n_in,
                              void* d_out, int out_size, void* d_ws, size_t ws_size,
                              hipStream_t stream) {
  const float* token  = (const float*)d_in[0];
  const float* routed = (const float*)d_in[1];
  const float* simrow = (const float*)d_in[2];
  const float* delta  = (const float*)d_in[3];
  const float* Wl     = (const float*)d_in[4];
  const float* bl     = (const float*)d_in[5];
  const float* gamma  = (const float*)d_in[6];
  const float* beta   = (const float*)d_in[7];
  const float* Wg     = (const float*)d_in[8];
  const float* bg     = (const float*)d_in[9];

  char* ws = (char*)d_ws;
  ushort* Bmain = (ushort*)(ws);                         // 4 MB
  ushort* Bk1   = (ushort*)(ws + (4u << 20));            // 2 MB
  ushort* Bgate = (ushort*)(ws + (6u << 20));            // 4 MB
  float*  tpart = (float*)(ws + (10u << 20));            // 16 MB

  float* out_arg  = (float*)d_out;
  float* out_gate = out_arg + (size_t)4096 * 1024;

  prep_kernel<<<1280, 256, 0, stream>>>(Wl, Wg, Bmain, Bk1, Bgate);
  gemm_small<32, 32, 0><<<dim3(64, 8), 256, 0, stream>>>(
      token, token, Bk1, bl, tpart);
  main_kernel<<<2048, 512, 0, stream>>>(
      routed, delta, simrow, Bmain, tpart, gamma, beta, out_arg);
  gemm_small<64, 32, 1><<<dim3(64, 8), 256, 0, stream>>>(
      token, out_arg, Bgate, bg, out_gate);
}

// Round 15
// 516.402 us; speedup vs baseline: 1.4346x; 1.4346x over previous
//
#include <hip/hip_runtime.h>
#include <hip/hip_bf16.h>

// Problem constants: D=1024, N=4096, K=16, M = N*K = 65536, K-dim main = 2048

typedef __attribute__((ext_vector_type(4))) float f32x4;
typedef __attribute__((ext_vector_type(2))) float f32x2;
typedef __attribute__((ext_vector_type(8))) short bf16x8;

__device__ __forceinline__ ushort f2bf(float f) {
  unsigned b = __builtin_bit_cast(unsigned, f);
  b += 0x7FFFu + ((b >> 16) & 1u);   // RNE
  return (ushort)(b >> 16);
}
__device__ __forceinline__ unsigned pk2(float a, float b) {
  return (unsigned)f2bf(a) | ((unsigned)f2bf(b) << 16);
}

// LDS XOR swizzle for the A tile (verified R1/R4/R6-R13)
__device__ __forceinline__ unsigned swz(unsigned a) {
  return a ^ (((a >> 7) & 3u) << 4);
}

__device__ __forceinline__ bf16x8 cvt8(const float* p) {
  f32x4 a = *(const f32x4*)p;
  f32x4 b = *(const f32x4*)(p + 4);
  bf16x8 r;
  r[0] = (short)f2bf(a[0]); r[1] = (short)f2bf(a[1]);
  r[2] = (short)f2bf(a[2]); r[3] = (short)f2bf(a[3]);
  r[4] = (short)f2bf(b[0]); r[5] = (short)f2bf(b[1]);
  r[6] = (short)f2bf(b[2]); r[7] = (short)f2bf(b[3]);
  return r;
}

// Non-temporal load for READ-ONCE streams only (main's A; R13: +8%).
// NOT used in gemm_small: its A operands are re-read 8x via grid.y
// duplication -- NT there turned L2/L3 hits into 8x HBM streams (R13's
// non-main time 88->136us regression, reverted here).
__device__ __forceinline__ f32x2 ntld2(const float* p) {
  return __builtin_nontemporal_load((const f32x2*)p);
}

// ---------------------------------------------------------------------------
// prep: LDS tile-transpose weight packer (verified green R4-R14).
// mode 0 (bid<512):  Bmain packed layout: flat = kt*32768 + wg*4096 + c*8 + m,
//                    chunk c = nf*64 + lane; value = Wl[1024+kt*32+(lane>>4)*8+m]
//                                                      [wg*128+nf*16+(lane&15)]
// mode 1 (512..768): Bk1 layout [kt][nn][q*8+m] from Wl rows 0..1023
// mode 2 (768..1280): Bgate same layout from Wg rows kt*32 (+ row+1024 summed
//                    when kt>=32)
// ---------------------------------------------------------------------------
__global__ __launch_bounds__(256) void prep_kernel(
    const float* __restrict__ Wl, const float* __restrict__ Wg,
    ushort* __restrict__ Bmain, ushort* __restrict__ Bk1,
    ushort* __restrict__ Bgate) {
  __shared__ float L[32][129];
  int t = threadIdx.x;
  int bid = blockIdx.x;
  const float* src; int row0, mode, kt, wg; ushort* dst;
  if (bid < 512)      { mode = 0; kt = bid >> 3;        wg = bid & 7; src = Wl; row0 = 1024 + kt * 32; dst = Bmain; }
  else if (bid < 768) { mode = 1; kt = (bid - 512) >> 3; wg = (bid - 512) & 7; src = Wl; row0 = kt * 32; dst = Bk1; }
  else                { mode = 2; kt = (bid - 768) >> 3; wg = (bid - 768) & 7; src = Wg; row0 = kt * 32; dst = Bgate; }
  int col0 = wg * 128;
  bool dosum = (mode == 2) && (kt >= 32);
#pragma unroll
  for (int p = 0; p < 4; ++p) {
    int r = p * 8 + (t >> 5), c = (t & 31) * 4;
    const float* sp = src + (size_t)(row0 + r) * 1024 + col0 + c;
    f32x4 v = *(const f32x4*)sp;
    if (dosum) { f32x4 v2 = *(const f32x4*)(sp + (size_t)1024 * 1024); v += v2; }
    L[r][c] = v[0]; L[r][c + 1] = v[1]; L[r][c + 2] = v[2]; L[r][c + 3] = v[3];
  }
  __syncthreads();
  if (mode == 0) {
    for (int c = t; c < 512; c += 256) {
      int nf = c >> 6, lane = c & 63, lr_ = lane & 15, lh_ = lane >> 4;
      bf16x8 o;
#pragma unroll
      for (int m = 0; m < 8; ++m) o[m] = (short)f2bf(L[lh_ * 8 + m][nf * 16 + lr_]);
      *(bf16x8*)(dst + (size_t)kt * 32768 + wg * 4096 + c * 8) = o;
    }
  } else {
    for (int c = t; c < 512; c += 256) {
      int nn = c >> 2, q = c & 3;
      bf16x8 o;
#pragma unroll
      for (int m = 0; m < 8; ++m) o[m] = (short)f2bf(L[q * 8 + m][nn]);
      *(bf16x8*)(dst + (size_t)kt * 32768 + (size_t)(wg * 128 + nn) * 32 + q * 8) = o;
    }
  }
}

// ---------------------------------------------------------------------------
// gemm_small: C = act(A_f32 @ Bpack + bias). 64x128 tile, 4 waves (2x2),
// wave tile 32x64. grid (M/64, 8) = 512 blocks -> 2 blocks/CU.
// Exact R10 version (normal cached A loads -- NT regressed, see above).
// ---------------------------------------------------------------------------
template <int NKT, int NSPLIT, int ACT>
__global__ __launch_bounds__(256) void gemm_small(
    const float* __restrict__ A0, const float* __restrict__ A1,
    const ushort* __restrict__ Bp, const float* __restrict__ bias,
    float* __restrict__ Cout) {
  int tid = threadIdx.x, l = tid & 63, wid = tid >> 6;
  int wm = wid & 1, wn = wid >> 1;
  int mbase = blockIdx.x * 64 + wm * 32;
  int nbase = blockIdx.y * 128 + wn * 64;
  int lr = l & 15, lh = l >> 4;
  f32x4 acc[2][4] = {};
#pragma unroll 1
  for (int kt = 0; kt < NKT; ++kt) {
    const float* As = (kt < NSPLIT) ? A0 : A1;
    int ke = ((kt < NSPLIT) ? kt : kt - NSPLIT) * 32 + lh * 8;
    bf16x8 af[2];
#pragma unroll
    for (int mf = 0; mf < 2; ++mf)
      af[mf] = cvt8(As + (size_t)(mbase + mf * 16 + lr) * 1024 + ke);
    bf16x8 bf[4];
#pragma unroll
    for (int nf = 0; nf < 4; ++nf)
      bf[nf] = *(const bf16x8*)(Bp + (size_t)kt * 32768 +
                                (size_t)(nbase + nf * 16 + lr) * 32 + lh * 8);
#pragma unroll
    for (int nf = 0; nf < 4; ++nf)
#pragma unroll
      for (int mf = 0; mf < 2; ++mf)
        acc[mf][nf] = __builtin_amdgcn_mfma_f32_16x16x32_bf16(
            af[mf], bf[nf], acc[mf][nf], 0, 0, 0);
  }
#pragma unroll
  for (int nf = 0; nf < 4; ++nf) {
    int col = nbase + nf * 16 + lr;
    float bs = bias[col];
#pragma unroll
    for (int mf = 0; mf < 2; ++mf)
#pragma unroll
      for (int j = 0; j < 4; ++j) {
        int row = mbase + mf * 16 + lh * 4 + j;
        float v = acc[mf][nf][j] + bs;
        if (ACT == 1) v = 1.0f / (1.0f + expf(-v));
        Cout[(size_t)row * 1024 + col] = v;
      }
  }
}

// ---------------------------------------------------------------------------
// main fused kernel — R13 structure (best measured: 411us; 16 waves x 64x64,
// acc[4][4], reg-dbuf B 1 ahead, A f32->reg->bf16->swizzled LDS dbuf, raw
// s_barrier + lgkmcnt(0) only, NT on the read-once A stream) with:
//  (1) WRITE-EARLY A-staging: the ds_write of tile kt+1 moves ABOVE the MFMA
//      block. Its value landed a full step ago (vmcnt-covered) and the
//      previous barrier already drained that buffer's readers, so the
//      protocol is unchanged (still 1 barrier/step) — this removes the
//      write+flush from the post-MFMA critical path (~150-200cy/step).
//  (2) Sigmoid-form fast GELU in the epilogue (overflow-safe; max deviation
//      from exact-erf GELU ~3e-4 vs 0.076 absmax headroom).
// ---------------------------------------------------------------------------
#define MFMA_STEP(ABSYM, BF) do {                                         \
  const char* ab_ = (const char*)(ABSYM) + aoff0;                         \
  bf16x8 af_[4];                                                          \
  _Pragma("unroll")                                                       \
  for (int mf = 0; mf < 4; ++mf)                                          \
    af_[mf] = *(const bf16x8*)(ab_ + mf * 1024);                          \
  _Pragma("unroll")                                                       \
  for (int nf = 0; nf < 4; ++nf)                                          \
    _Pragma("unroll")                                                     \
    for (int mf = 0; mf < 4; ++mf)                                        \
      acc[mf][nf] = __builtin_amdgcn_mfma_f32_16x16x32_bf16(              \
          af_[mf], (BF)[nf], acc[mf][nf], 0, 0, 0);                       \
} while (0)

// Raw barrier: LDS ordering only; VGPR-dest global loads stay in flight.
#define BARRIER_LG() do {                                                 \
  asm volatile("s_waitcnt lgkmcnt(0)" ::: "memory");                      \
  __builtin_amdgcn_s_barrier();                                           \
  asm volatile("" ::: "memory");                                          \
} while (0)

__global__ __launch_bounds__(1024) void main_kernel(
    const float* __restrict__ routed, const float* __restrict__ delta,
    const float* __restrict__ simrow, const ushort* __restrict__ Bmain,
    const float* __restrict__ tpart, const float* __restrict__ gamma,
    const float* __restrict__ beta, float* __restrict__ out_arg) {
  __shared__ ushort Ab0[2048];          // 4KB A tile [64][32] bf16 (swz)
  __shared__ ushort Ab1[2048];
  __shared__ float ldsW[64];            // softmax weights 4 tokens x 16 k
  __shared__ float lnS[64 * 16], lnQ[64 * 16];

  int tid = threadIdx.x, l = tid & 63, wid = tid >> 6;   // wid 0..15
  int bx = blockIdx.x;                  // tokens bx*4 .. bx*4+3
  int lr = l & 15, lh = l >> 4;

  if (tid < 4) {                        // softmax over K=16 for token bx*4+tid
    int n = bx * 4 + tid;
    float sv[16], mx = -1e30f;
#pragma unroll
    for (int j = 0; j < 16; ++j) { sv[j] = simrow[n * 16 + j]; mx = fmaxf(mx, sv[j]); }
    float s = 0.f;
#pragma unroll
    for (int j = 0; j < 16; ++j) { sv[j] = expf(sv[j] - mx); s += sv[j]; }
    float inv = 1.0f / s;
#pragma unroll
    for (int j = 0; j < 16; ++j) ldsW[tid * 16 + j] = sv[j] * inv;
  }

  // A staging geometry: 1024 threads x 4B of the 4KB tile.
  const float* rbase = routed + (size_t)(bx * 64 + (tid >> 4)) * 1024 + (tid & 15) * 2;
  const float* dbase = delta  + (size_t)(bx * 64 + (tid >> 4)) * 1024 + (tid & 15) * 2;
  const unsigned adst = swz((unsigned)tid * 4);

  // A-tile read base offset (swz XOR independent of mf; +mf*1024 folds to imm)
  const unsigned aoff0 = swz((unsigned)lr * 64 + (unsigned)lh * 16);

  // B per-lane pointer: wave wid covers cols wid*64 + nf*16 + lr.
  // packed: wg = wid>>1, chunk = ((wid&1)*4+nf)*64 + l -> 16B/lane coalesced
  const ushort* bptr = Bmain + (size_t)(wid >> 1) * 4096 +
                       (size_t)(wid & 1) * 2048 + (size_t)l * 8;

  // ---- prologue: A(0)->Ab0, A(1)->avA, B(0)->bfA ----
  f32x2 t0 = ntld2(rbase);
  f32x2 avA = ntld2(rbase + 32);
  f32x2 avB;
  bf16x8 bfA[4], bfB[4];
#pragma unroll
  for (int nf = 0; nf < 4; ++nf)
    bfA[nf] = *(const bf16x8*)(bptr + nf * 512);
  *(unsigned*)((char*)Ab0 + adst) = pk2(t0[0], t0[1]);
  BARRIER_LG();

  f32x4 acc[4][4] = {};
#pragma unroll 1
  for (int kt = 0; kt < 64; kt += 2) {
    // ===== even step: consume Ab0 + bfA =====
    {                                    // A(kt+2) issued, stays in flight
      const float* as_ = (kt + 2 < 32) ? rbase : dbase;
      avB = ntld2(as_ + (size_t)((kt + 2) & 31) * 32);
    }
#pragma unroll
    for (int nf = 0; nf < 4; ++nf)       // B(kt+1) issued, stays in flight
      bfB[nf] = *(const bf16x8*)(bptr + 32768 + nf * 512);
    *(unsigned*)((char*)Ab1 + adst) = pk2(avA[0], avA[1]);   // A(kt+1) early
    MFMA_STEP(Ab0, bfA);
    BARRIER_LG();
    // ===== odd step: consume Ab1 + bfB =====
    {                                    // A(kt+3) (benign over-read at end)
      const float* as_ = (kt + 3 < 32) ? rbase : dbase;
      avA = ntld2(as_ + (size_t)((kt + 3) & 31) * 32);
    }
#pragma unroll
    for (int nf = 0; nf < 4; ++nf)       // B(kt+2) (benign over-read at end)
      bfA[nf] = *(const bf16x8*)(bptr + 65536 + nf * 512);
    *(unsigned*)((char*)Ab0 + adst) = pk2(avB[0], avB[1]);   // A(kt+2) early
    MFMA_STEP(Ab1, bfB);
    BARRIER_LG();
    bptr += 65536;
  }

  // ---- fused epilogue (sigmoid-form fast GELU; tpart NT = read-once) ----
  // acc[mf][nf][j]: local row mf*16 + lh*4 + j (= token mf, k = lh*4+j),
  //                 col wid*64 + nf*16 + lr
  const float inv_d = 1.0f / 1024.0f;
  float gam[4], bet[4];
#pragma unroll
  for (int nf = 0; nf < 4; ++nf) {
    int c = wid * 64 + nf * 16 + lr;
    gam[nf] = gamma[c]; bet[nf] = beta[c];
  }
#pragma unroll
  for (int mf = 0; mf < 4; ++mf) {
    int tokrow = bx * 4 + mf;
    float s[4] = {0, 0, 0, 0}, q[4] = {0, 0, 0, 0};
#pragma unroll
    for (int nf = 0; nf < 4; ++nf) {
      float tp = __builtin_nontemporal_load(
          tpart + (size_t)tokrow * 1024 + wid * 64 + nf * 16 + lr);
#pragma unroll
      for (int j = 0; j < 4; ++j) {
        float h = acc[mf][nf][j] + tp;
        // gelu(h) = h * sigmoid(1.595769f*h + 0.071355f*h^3)  (tanh form;
        // max dev from exact-erf gelu ~3e-4; overflow-safe: exp->inf -> g->0)
        float u = h * (1.5957691f + 0.07135481f * h * h);
        float g = h / (1.0f + __expf(-u));
        acc[mf][nf][j] = g;
        s[j] += g; q[j] += g * g;
      }
    }
#pragma unroll
    for (int j = 0; j < 4; ++j) {
#pragma unroll
      for (int d = 1; d <= 8; d <<= 1) {
        s[j] += __shfl_xor(s[j], d, 64);
        q[j] += __shfl_xor(q[j], d, 64);
      }
    }
    if (lr == 0) {
#pragma unroll
      for (int j = 0; j < 4; ++j) {
        int row = mf * 16 + lh * 4 + j;
        lnS[row * 16 + wid] = s[j];
        lnQ[row * 16 + wid] = q[j];
      }
    }
  }
  __syncthreads();
#pragma unroll
  for (int mf = 0; mf < 4; ++mf) {
    float mu[4], rs[4], wk[4];
#pragma unroll
    for (int j = 0; j < 4; ++j) {
      int row = mf * 16 + lh * 4 + j;
      float S = 0.f, Q = 0.f;
#pragma unroll
      for (int w4 = 0; w4 < 4; ++w4) {
        f32x4 vs = *(const f32x4*)&lnS[row * 16 + w4 * 4];
        f32x4 vq = *(const f32x4*)&lnQ[row * 16 + w4 * 4];
        S += vs[0] + vs[1] + vs[2] + vs[3];
        Q += vq[0] + vq[1] + vq[2] + vq[3];
      }
      float m_ = S * inv_d;
      mu[j] = m_;
      rs[j] = rsqrtf(Q * inv_d - m_ * m_ + 1e-5f);
      wk[j] = ldsW[row];
    }
#pragma unroll
    for (int nf = 0; nf < 4; ++nf) {
      float ws = 0.f;
#pragma unroll
      for (int j = 0; j < 4; ++j) {
        float y = (acc[mf][nf][j] - mu[j]) * rs[j] * gam[nf] + bet[nf];
        ws += wk[j] * y;
      }
      ws += __shfl_xor(ws, 16, 64);
      ws += __shfl_xor(ws, 32, 64);
      if (lh == 0)
        out_arg[(size_t)(bx * 4 + mf) * 1024 + wid * 64 + nf * 16 + lr] = ws;
    }
  }
}

// ---------------------------------------------------------------------------
extern "C" void kernel_launch(void* const* d_in, const int* in_sizes, int n_in,
                              void* d_out, int out_size, void* d_ws, size_t ws_size,
                              hipStream_t stream) {
  const float* token  = (const float*)d_in[0];
  const float* routed = (const float*)d_in[1];
  const float* simrow = (const float*)d_in[2];
  const float* delta  = (const float*)d_in[3];
  const float* Wl     = (const float*)d_in[4];
  const float* bl     = (const float*)d_in[5];
  const float* gamma  = (const float*)d_in[6];
  const float* beta   = (const float*)d_in[7];
  const float* Wg     = (const float*)d_in[8];
  const float* bg     = (const float*)d_in[9];

  char* ws = (char*)d_ws;
  ushort* Bmain = (ushort*)(ws);                         // 4 MB
  ushort* Bk1   = (ushort*)(ws + (4u << 20));            // 2 MB
  ushort* Bgate = (ushort*)(ws + (6u << 20));            // 4 MB
  float*  tpart = (float*)(ws + (10u << 20));            // 16 MB

  float* out_arg  = (float*)d_out;
  float* out_gate = out_arg + (size_t)4096 * 1024;

  prep_kernel<<<1280, 256, 0, stream>>>(Wl, Wg, Bmain, Bk1, Bgate);
  gemm_small<32, 32, 0><<<dim3(64, 8), 256, 0, stream>>>(
      token, token, Bk1, bl, tpart);
  main_kernel<<<1024, 1024, 0, stream>>>(
      routed, delta, simrow, Bmain, tpart, gamma, beta, out_arg);
  gemm_small<64, 32, 1><<<dim3(64, 8), 256, 0, stream>>>(
      token, out_arg, Bgate, bg, out_gate);
}

// Round 16
// 479.401 us; speedup vs baseline: 1.5454x; 1.0772x over previous
//
#include <hip/hip_runtime.h>
#include <hip/hip_bf16.h>

// Problem constants: D=1024, N=4096, K=16, M = N*K = 65536, K-dim main = 2048

typedef __attribute__((ext_vector_type(4))) float f32x4;
typedef __attribute__((ext_vector_type(2))) float f32x2;
typedef __attribute__((ext_vector_type(8))) short bf16x8;

__device__ __forceinline__ ushort f2bf(float f) {
  unsigned b = __builtin_bit_cast(unsigned, f);
  b += 0x7FFFu + ((b >> 16) & 1u);   // RNE
  return (ushort)(b >> 16);
}
__device__ __forceinline__ unsigned pk2(float a, float b) {
  return (unsigned)f2bf(a) | ((unsigned)f2bf(b) << 16);
}

// LDS XOR swizzle for the A tile (verified R1/R4/R6-R15)
__device__ __forceinline__ unsigned swz(unsigned a) {
  return a ^ (((a >> 7) & 3u) << 4);
}

// Non-temporal load for READ-ONCE streams only (main's A; R13: +8%).
__device__ __forceinline__ f32x2 ntld2(const float* p) {
  return __builtin_nontemporal_load((const f32x2*)p);
}

// ---------------------------------------------------------------------------
// prep: LDS tile-transpose weight packer (verified green R4-R15) + mode 3:
// token f32 -> bf16 row-major copy (RNE; bit-identical to the cvt the gemms
// previously applied per-load — now done once to halve their A traffic).
// mode 0 (bid<512):  Bmain packed layout: flat = kt*32768 + wg*4096 + c*8 + m
// mode 1 (512..768): Bk1 layout [kt][nn][q*8+m] from Wl rows 0..1023
// mode 2 (768..1280): Bgate same layout from Wg (rows kt*32, +1024 summed
//                    when kt>=32)
// mode 3 (1280..1536): tokenb[i] = bf16(token[i]), 16 rows/block
// ---------------------------------------------------------------------------
__global__ __launch_bounds__(256) void prep_kernel(
    const float* __restrict__ Wl, const float* __restrict__ Wg,
    const float* __restrict__ token,
    ushort* __restrict__ Bmain, ushort* __restrict__ Bk1,
    ushort* __restrict__ Bgate, ushort* __restrict__ tokenb) {
  int t = threadIdx.x;
  int bid = blockIdx.x;
  if (bid >= 1280) {                    // mode 3: token -> bf16
    size_t base = (size_t)(bid - 1280) * 16384;
#pragma unroll
    for (int it = 0; it < 16; ++it) {
      size_t e = base + (size_t)it * 1024 + t * 4;
      f32x4 v = *(const f32x4*)(token + e);
      uint2 o; o.x = pk2(v[0], v[1]); o.y = pk2(v[2], v[3]);
      *(uint2*)(tokenb + e) = o;
    }
    return;
  }
  __shared__ float L[32][129];
  const float* src; int row0, mode, kt, wg; ushort* dst;
  if (bid < 512)      { mode = 0; kt = bid >> 3;        wg = bid & 7; src = Wl; row0 = 1024 + kt * 32; dst = Bmain; }
  else if (bid < 768) { mode = 1; kt = (bid - 512) >> 3; wg = (bid - 512) & 7; src = Wl; row0 = kt * 32; dst = Bk1; }
  else                { mode = 2; kt = (bid - 768) >> 3; wg = (bid - 768) & 7; src = Wg; row0 = kt * 32; dst = Bgate; }
  int col0 = wg * 128;
  bool dosum = (mode == 2) && (kt >= 32);
#pragma unroll
  for (int p = 0; p < 4; ++p) {
    int r = p * 8 + (t >> 5), c = (t & 31) * 4;
    const float* sp = src + (size_t)(row0 + r) * 1024 + col0 + c;
    f32x4 v = *(const f32x4*)sp;
    if (dosum) { f32x4 v2 = *(const f32x4*)(sp + (size_t)1024 * 1024); v += v2; }
    L[r][c] = v[0]; L[r][c + 1] = v[1]; L[r][c + 2] = v[2]; L[r][c + 3] = v[3];
  }
  __syncthreads();
  if (mode == 0) {
    for (int c = t; c < 512; c += 256) {
      int nf = c >> 6, lane = c & 63, lr_ = lane & 15, lh_ = lane >> 4;
      bf16x8 o;
#pragma unroll
      for (int m = 0; m < 8; ++m) o[m] = (short)f2bf(L[lh_ * 8 + m][nf * 16 + lr_]);
      *(bf16x8*)(dst + (size_t)kt * 32768 + wg * 4096 + c * 8) = o;
    }
  } else {
    for (int c = t; c < 512; c += 256) {
      int nn = c >> 2, q = c & 3;
      bf16x8 o;
#pragma unroll
      for (int m = 0; m < 8; ++m) o[m] = (short)f2bf(L[q * 8 + m][nn]);
      *(bf16x8*)(dst + (size_t)kt * 32768 + (size_t)(wg * 128 + nn) * 32 + q * 8) = o;
    }
  }
}

// ---------------------------------------------------------------------------
// gemm_small_b: C = act(A_bf16 @ Bpack + bias). 64x128 tile, 4 waves (2x2),
// wave tile 32x64, grid (M/64, 8). Same geometry as the green R10/R15
// gemm_small but A is pre-rounded bf16 (direct bf16x8 loads, no cvt chain,
// half the A bytes). Numerics bit-identical (same RNE rounding point).
// ---------------------------------------------------------------------------
template <int NKT, int NSPLIT, int ACT>
__global__ __launch_bounds__(256) void gemm_small_b(
    const ushort* __restrict__ A0, const ushort* __restrict__ A1,
    const ushort* __restrict__ Bp, const float* __restrict__ bias,
    float* __restrict__ Cout) {
  int tid = threadIdx.x, l = tid & 63, wid = tid >> 6;
  int wm = wid & 1, wn = wid >> 1;
  int mbase = blockIdx.x * 64 + wm * 32;
  int nbase = blockIdx.y * 128 + wn * 64;
  int lr = l & 15, lh = l >> 4;
  f32x4 acc[2][4] = {};
#pragma unroll 1
  for (int kt = 0; kt < NKT; ++kt) {
    const ushort* As = (kt < NSPLIT) ? A0 : A1;
    int ke = ((kt < NSPLIT) ? kt : kt - NSPLIT) * 32 + lh * 8;
    bf16x8 af[2];
#pragma unroll
    for (int mf = 0; mf < 2; ++mf)
      af[mf] = *(const bf16x8*)(As + (size_t)(mbase + mf * 16 + lr) * 1024 + ke);
    bf16x8 bf[4];
#pragma unroll
    for (int nf = 0; nf < 4; ++nf)
      bf[nf] = *(const bf16x8*)(Bp + (size_t)kt * 32768 +
                                (size_t)(nbase + nf * 16 + lr) * 32 + lh * 8);
#pragma unroll
    for (int nf = 0; nf < 4; ++nf)
#pragma unroll
      for (int mf = 0; mf < 2; ++mf)
        acc[mf][nf] = __builtin_amdgcn_mfma_f32_16x16x32_bf16(
            af[mf], bf[nf], acc[mf][nf], 0, 0, 0);
  }
#pragma unroll
  for (int nf = 0; nf < 4; ++nf) {
    int col = nbase + nf * 16 + lr;
    float bs = bias[col];
#pragma unroll
    for (int mf = 0; mf < 2; ++mf)
#pragma unroll
      for (int j = 0; j < 4; ++j) {
        int row = mbase + mf * 16 + lh * 4 + j;
        float v = acc[mf][nf][j] + bs;
        if (ACT == 1) v = 1.0f / (1.0f + expf(-v));
        Cout[(size_t)row * 1024 + col] = v;
      }
  }
}

// ---------------------------------------------------------------------------
// main fused kernel — R15 green structure, FROZEN except one extra store:
// the epilogue also writes arg as bf16 (argb) for the gate gemm's A1 (same
// RNE rounding the gate gemm previously applied per-load; bit-identical).
// Structure: 16 waves x 64x64, acc[4][4], reg-dbuf B 1 ahead, A f32->reg->
// bf16->swizzled LDS dbuf (write-early), raw s_barrier + lgkmcnt(0) only,
// NT on read-once A stream, sigmoid-form fast GELU.
// ---------------------------------------------------------------------------
#define MFMA_STEP(ABSYM, BF) do {                                         \
  const char* ab_ = (const char*)(ABSYM) + aoff0;                         \
  bf16x8 af_[4];                                                          \
  _Pragma("unroll")                                                       \
  for (int mf = 0; mf < 4; ++mf)                                          \
    af_[mf] = *(const bf16x8*)(ab_ + mf * 1024);                          \
  _Pragma("unroll")                                                       \
  for (int nf = 0; nf < 4; ++nf)                                          \
    _Pragma("unroll")                                                     \
    for (int mf = 0; mf < 4; ++mf)                                        \
      acc[mf][nf] = __builtin_amdgcn_mfma_f32_16x16x32_bf16(              \
          af_[mf], (BF)[nf], acc[mf][nf], 0, 0, 0);                       \
} while (0)

#define BARRIER_LG() do {                                                 \
  asm volatile("s_waitcnt lgkmcnt(0)" ::: "memory");                      \
  __builtin_amdgcn_s_barrier();                                           \
  asm volatile("" ::: "memory");                                          \
} while (0)

__global__ __launch_bounds__(1024) void main_kernel(
    const float* __restrict__ routed, const float* __restrict__ delta,
    const float* __restrict__ simrow, const ushort* __restrict__ Bmain,
    const float* __restrict__ tpart, const float* __restrict__ gamma,
    const float* __restrict__ beta, float* __restrict__ out_arg,
    ushort* __restrict__ argb) {
  __shared__ ushort Ab0[2048];          // 4KB A tile [64][32] bf16 (swz)
  __shared__ ushort Ab1[2048];
  __shared__ float ldsW[64];            // softmax weights 4 tokens x 16 k
  __shared__ float lnS[64 * 16], lnQ[64 * 16];

  int tid = threadIdx.x, l = tid & 63, wid = tid >> 6;   // wid 0..15
  int bx = blockIdx.x;                  // tokens bx*4 .. bx*4+3
  int lr = l & 15, lh = l >> 4;

  if (tid < 4) {                        // softmax over K=16 for token bx*4+tid
    int n = bx * 4 + tid;
    float sv[16], mx = -1e30f;
#pragma unroll
    for (int j = 0; j < 16; ++j) { sv[j] = simrow[n * 16 + j]; mx = fmaxf(mx, sv[j]); }
    float s = 0.f;
#pragma unroll
    for (int j = 0; j < 16; ++j) { sv[j] = expf(sv[j] - mx); s += sv[j]; }
    float inv = 1.0f / s;
#pragma unroll
    for (int j = 0; j < 16; ++j) ldsW[tid * 16 + j] = sv[j] * inv;
  }

  // A staging geometry: 1024 threads x 4B of the 4KB tile.
  const float* rbase = routed + (size_t)(bx * 64 + (tid >> 4)) * 1024 + (tid & 15) * 2;
  const float* dbase = delta  + (size_t)(bx * 64 + (tid >> 4)) * 1024 + (tid & 15) * 2;
  const unsigned adst = swz((unsigned)tid * 4);

  // A-tile read base offset (swz XOR independent of mf; +mf*1024 folds to imm)
  const unsigned aoff0 = swz((unsigned)lr * 64 + (unsigned)lh * 16);

  // B per-lane pointer: wave wid covers cols wid*64 + nf*16 + lr.
  const ushort* bptr = Bmain + (size_t)(wid >> 1) * 4096 +
                       (size_t)(wid & 1) * 2048 + (size_t)l * 8;

  // ---- prologue: A(0)->Ab0, A(1)->avA, B(0)->bfA ----
  f32x2 t0 = ntld2(rbase);
  f32x2 avA = ntld2(rbase + 32);
  f32x2 avB;
  bf16x8 bfA[4], bfB[4];
#pragma unroll
  for (int nf = 0; nf < 4; ++nf)
    bfA[nf] = *(const bf16x8*)(bptr + nf * 512);
  *(unsigned*)((char*)Ab0 + adst) = pk2(t0[0], t0[1]);
  BARRIER_LG();

  f32x4 acc[4][4] = {};
#pragma unroll 1
  for (int kt = 0; kt < 64; kt += 2) {
    // ===== even step: consume Ab0 + bfA =====
    {                                    // A(kt+2) issued, stays in flight
      const float* as_ = (kt + 2 < 32) ? rbase : dbase;
      avB = ntld2(as_ + (size_t)((kt + 2) & 31) * 32);
    }
#pragma unroll
    for (int nf = 0; nf < 4; ++nf)       // B(kt+1) issued, stays in flight
      bfB[nf] = *(const bf16x8*)(bptr + 32768 + nf * 512);
    *(unsigned*)((char*)Ab1 + adst) = pk2(avA[0], avA[1]);   // A(kt+1) early
    MFMA_STEP(Ab0, bfA);
    BARRIER_LG();
    // ===== odd step: consume Ab1 + bfB =====
    {                                    // A(kt+3) (benign over-read at end)
      const float* as_ = (kt + 3 < 32) ? rbase : dbase;
      avA = ntld2(as_ + (size_t)((kt + 3) & 31) * 32);
    }
#pragma unroll
    for (int nf = 0; nf < 4; ++nf)       // B(kt+2) (benign over-read at end)
      bfA[nf] = *(const bf16x8*)(bptr + 65536 + nf * 512);
    *(unsigned*)((char*)Ab0 + adst) = pk2(avB[0], avB[1]);   // A(kt+2) early
    MFMA_STEP(Ab1, bfB);
    BARRIER_LG();
    bptr += 65536;
  }

  // ---- fused epilogue (sigmoid-form fast GELU; tpart NT = read-once) ----
  const float inv_d = 1.0f / 1024.0f;
  float gam[4], bet[4];
#pragma unroll
  for (int nf = 0; nf < 4; ++nf) {
    int c = wid * 64 + nf * 16 + lr;
    gam[nf] = gamma[c]; bet[nf] = beta[c];
  }
#pragma unroll
  for (int mf = 0; mf < 4; ++mf) {
    int tokrow = bx * 4 + mf;
    float s[4] = {0, 0, 0, 0}, q[4] = {0, 0, 0, 0};
#pragma unroll
    for (int nf = 0; nf < 4; ++nf) {
      float tp = __builtin_nontemporal_load(
          tpart + (size_t)tokrow * 1024 + wid * 64 + nf * 16 + lr);
#pragma unroll
      for (int j = 0; j < 4; ++j) {
        float h = acc[mf][nf][j] + tp;
        float u = h * (1.5957691f + 0.07135481f * h * h);
        float g = h / (1.0f + __expf(-u));
        acc[mf][nf][j] = g;
        s[j] += g; q[j] += g * g;
      }
    }
#pragma unroll
    for (int j = 0; j < 4; ++j) {
#pragma unroll
      for (int d = 1; d <= 8; d <<= 1) {
        s[j] += __shfl_xor(s[j], d, 64);
        q[j] += __shfl_xor(q[j], d, 64);
      }
    }
    if (lr == 0) {
#pragma unroll
      for (int j = 0; j < 4; ++j) {
        int row = mf * 16 + lh * 4 + j;
        lnS[row * 16 + wid] = s[j];
        lnQ[row * 16 + wid] = q[j];
      }
    }
  }
  __syncthreads();
#pragma unroll
  for (int mf = 0; mf < 4; ++mf) {
    float mu[4], rs[4], wk[4];
#pragma unroll
    for (int j = 0; j < 4; ++j) {
      int row = mf * 16 + lh * 4 + j;
      float S = 0.f, Q = 0.f;
#pragma unroll
      for (int w4 = 0; w4 < 4; ++w4) {
        f32x4 vs = *(const f32x4*)&lnS[row * 16 + w4 * 4];
        f32x4 vq = *(const f32x4*)&lnQ[row * 16 + w4 * 4];
        S += vs[0] + vs[1] + vs[2] + vs[3];
        Q += vq[0] + vq[1] + vq[2] + vq[3];
      }
      float m_ = S * inv_d;
      mu[j] = m_;
      rs[j] = rsqrtf(Q * inv_d - m_ * m_ + 1e-5f);
      wk[j] = ldsW[row];
    }
#pragma unroll
    for (int nf = 0; nf < 4; ++nf) {
      float ws = 0.f;
#pragma unroll
      for (int j = 0; j < 4; ++j) {
        float y = (acc[mf][nf][j] - mu[j]) * rs[j] * gam[nf] + bet[nf];
        ws += wk[j] * y;
      }
      ws += __shfl_xor(ws, 16, 64);
      ws += __shfl_xor(ws, 32, 64);
      if (lh == 0) {
        size_t oidx = (size_t)(bx * 4 + mf) * 1024 + wid * 64 + nf * 16 + lr;
        out_arg[oidx] = ws;
        argb[oidx] = f2bf(ws);   // bf16 copy for the gate gemm's A1
      }
    }
  }
}

// ---------------------------------------------------------------------------
extern "C" void kernel_launch(void* const* d_in, const int* in_sizes, int n_in,
                              void* d_out, int out_size, void* d_ws, size_t ws_size,
                              hipStream_t stream) {
  const float* token  = (const float*)d_in[0];
  const float* routed = (const float*)d_in[1];
  const float* simrow = (const float*)d_in[2];
  const float* delta  = (const float*)d_in[3];
  const float* Wl     = (const float*)d_in[4];
  const float* bl     = (const float*)d_in[5];
  const float* gamma  = (const float*)d_in[6];
  const float* beta   = (const float*)d_in[7];
  const float* Wg     = (const float*)d_in[8];
  const float* bg     = (const float*)d_in[9];

  char* ws = (char*)d_ws;
  ushort* Bmain  = (ushort*)(ws);                        // 4 MB
  ushort* Bk1    = (ushort*)(ws + (4u << 20));           // 2 MB
  ushort* Bgate  = (ushort*)(ws + (6u << 20));           // 4 MB
  float*  tpart  = (float*)(ws + (10u << 20));           // 16 MB
  ushort* tokenb = (ushort*)(ws + (26u << 20));          // 8 MB
  ushort* argb   = (ushort*)(ws + (34u << 20));          // 8 MB (total 42 MB)

  float* out_arg  = (float*)d_out;
  float* out_gate = out_arg + (size_t)4096 * 1024;

  prep_kernel<<<1536, 256, 0, stream>>>(Wl, Wg, token, Bmain, Bk1, Bgate, tokenb);
  gemm_small_b<32, 32, 0><<<dim3(64, 8), 256, 0, stream>>>(
      tokenb, tokenb, Bk1, bl, tpart);
  main_kernel<<<1024, 1024, 0, stream>>>(
      routed, delta, simrow, Bmain, tpart, gamma, beta, out_arg, argb);
  gemm_small_b<64, 32, 1><<<dim3(64, 8), 256, 0, stream>>>(
      tokenb, argb, Bgate, bg, out_gate);
}

// Round 18
// 476.295 us; speedup vs baseline: 1.5554x; 1.0065x over previous
//
#include <hip/hip_runtime.h>
#include <hip/hip_bf16.h>

// Problem constants: D=1024, N=4096, K=16, M = N*K = 65536, K-dim main = 2048

typedef __attribute__((ext_vector_type(4))) float f32x4;
typedef __attribute__((ext_vector_type(2))) float f32x2;
typedef __attribute__((ext_vector_type(8))) short bf16x8;

__device__ __forceinline__ ushort f2bf(float f) {
  unsigned b = __builtin_bit_cast(unsigned, f);
  b += 0x7FFFu + ((b >> 16) & 1u);   // RNE
  return (ushort)(b >> 16);
}
__device__ __forceinline__ unsigned pk2(float a, float b) {
  return (unsigned)f2bf(a) | ((unsigned)f2bf(b) << 16);
}

// ---------------------------------------------------------------------------
// prep: LDS tile-transpose weight packer (verified green R4-R16) + mode 3
// token f32 -> bf16 (RNE, bit-identical to per-load cvt).
// ---------------------------------------------------------------------------
__global__ __launch_bounds__(256) void prep_kernel(
    const float* __restrict__ Wl, const float* __restrict__ Wg,
    const float* __restrict__ token,
    ushort* __restrict__ Bmain, ushort* __restrict__ Bk1,
    ushort* __restrict__ Bgate, ushort* __restrict__ tokenb) {
  int t = threadIdx.x;
  int bid = blockIdx.x;
  if (bid >= 1280) {                    // mode 3: token -> bf16
    size_t base = (size_t)(bid - 1280) * 16384;
#pragma unroll
    for (int it = 0; it < 16; ++it) {
      size_t e = base + (size_t)it * 1024 + t * 4;
      f32x4 v = *(const f32x4*)(token + e);
      uint2 o; o.x = pk2(v[0], v[1]); o.y = pk2(v[2], v[3]);
      *(uint2*)(tokenb + e) = o;
    }
    return;
  }
  __shared__ float L[32][129];
  const float* src; int row0, mode, kt, wg; ushort* dst;
  if (bid < 512)      { mode = 0; kt = bid >> 3;        wg = bid & 7; src = Wl; row0 = 1024 + kt * 32; dst = Bmain; }
  else if (bid < 768) { mode = 1; kt = (bid - 512) >> 3; wg = (bid - 512) & 7; src = Wl; row0 = kt * 32; dst = Bk1; }
  else                { mode = 2; kt = (bid - 768) >> 3; wg = (bid - 768) & 7; src = Wg; row0 = kt * 32; dst = Bgate; }
  int col0 = wg * 128;
  bool dosum = (mode == 2) && (kt >= 32);
#pragma unroll
  for (int p = 0; p < 4; ++p) {
    int r = p * 8 + (t >> 5), c = (t & 31) * 4;
    const float* sp = src + (size_t)(row0 + r) * 1024 + col0 + c;
    f32x4 v = *(const f32x4*)sp;
    if (dosum) { f32x4 v2 = *(const f32x4*)(sp + (size_t)1024 * 1024); v += v2; }
    L[r][c] = v[0]; L[r][c + 1] = v[1]; L[r][c + 2] = v[2]; L[r][c + 3] = v[3];
  }
  __syncthreads();
  if (mode == 0) {
    for (int c = t; c < 512; c += 256) {
      int nf = c >> 6, lane = c & 63, lr_ = lane & 15, lh_ = lane >> 4;
      bf16x8 o;
#pragma unroll
      for (int m = 0; m < 8; ++m) o[m] = (short)f2bf(L[lh_ * 8 + m][nf * 16 + lr_]);
      *(bf16x8*)(dst + (size_t)kt * 32768 + wg * 4096 + c * 8) = o;
    }
  } else {
    for (int c = t; c < 512; c += 256) {
      int nn = c >> 2, q = c & 3;
      bf16x8 o;
#pragma unroll
      for (int m = 0; m < 8; ++m) o[m] = (short)f2bf(L[q * 8 + m][nn]);
      *(bf16x8*)(dst + (size_t)kt * 32768 + (size_t)(wg * 128 + nn) * 32 + q * 8) = o;
    }
  }
}

// ---------------------------------------------------------------------------
// gemm_small_b: C = act(A_bf16 @ Bpack + bias). 64x128 tile, 4 waves (2x2),
// wave tile 32x64, grid (M/64, 8). (green R16)
// ---------------------------------------------------------------------------
template <int NKT, int NSPLIT, int ACT>
__global__ __launch_bounds__(256) void gemm_small_b(
    const ushort* __restrict__ A0, const ushort* __restrict__ A1,
    const ushort* __restrict__ Bp, const float* __restrict__ bias,
    float* __restrict__ Cout) {
  int tid = threadIdx.x, l = tid & 63, wid = tid >> 6;
  int wm = wid & 1, wn = wid >> 1;
  int mbase = blockIdx.x * 64 + wm * 32;
  int nbase = blockIdx.y * 128 + wn * 64;
  int lr = l & 15, lh = l >> 4;
  f32x4 acc[2][4] = {};
#pragma unroll 1
  for (int kt = 0; kt < NKT; ++kt) {
    const ushort* As = (kt < NSPLIT) ? A0 : A1;
    int ke = ((kt < NSPLIT) ? kt : kt - NSPLIT) * 32 + lh * 8;
    bf16x8 af[2];
#pragma unroll
    for (int mf = 0; mf < 2; ++mf)
      af[mf] = *(const bf16x8*)(As + (size_t)(mbase + mf * 16 + lr) * 1024 + ke);
    bf16x8 bf[4];
#pragma unroll
    for (int nf = 0; nf < 4; ++nf)
      bf[nf] = *(const bf16x8*)(Bp + (size_t)kt * 32768 +
                                (size_t)(nbase + nf * 16 + lr) * 32 + lh * 8);
#pragma unroll
    for (int nf = 0; nf < 4; ++nf)
#pragma unroll
      for (int mf = 0; mf < 2; ++mf)
        acc[mf][nf] = __builtin_amdgcn_mfma_f32_16x16x32_bf16(
            af[mf], bf[nf], acc[mf][nf], 0, 0, 0);
  }
#pragma unroll
  for (int nf = 0; nf < 4; ++nf) {
    int col = nbase + nf * 16 + lr;
    float bs = bias[col];
#pragma unroll
    for (int mf = 0; mf < 2; ++mf)
#pragma unroll
      for (int j = 0; j < 4; ++j) {
        int row = mbase + mf * 16 + lh * 4 + j;
        float v = acc[mf][nf][j] + bs;
        if (ACT == 1) v = 1.0f / (1.0f + expf(-v));
        Cout[(size_t)row * 1024 + col] = v;
      }
  }
}

// ---------------------------------------------------------------------------
// main fused kernel — BARRIER-FREE K-LOOP via whole-half A staging (R17
// architecture; R17's crash was a STAGE_HALF indexing bug: j<16 with wrong
// strides read 60 floats past `delta` (page fault) and double-wrote LDS.
// Fixed here: j<8, src stride j*128 floats, dest (acol*16+j*256)^xw — exact
// row coverage, last global element = buffer end, LDS writes stay in-row).
// A staged as 128KB LDS [64 rows][2048B] bf16, one K-half at a time
// (routed, then delta), XOR-swizzle: chunk (row, kb) at kb^((row&7)<<4).
// K-loop 32 steps, ZERO barriers (Abig read-only, B reg-dbuf 1 ahead) ->
// waves drift, latencies overlap across waves. 5 __syncthreads total.
// lnS/lnQ overlay dead Abig in the epilogue.
// ---------------------------------------------------------------------------
#define STAGE_HALF(SRC) do {                                               \
  const float* sr_ = (SRC) + (size_t)(bx * 64 + arow) * 1024 + acol * 8;   \
  char* lw_ = smem + arow * 2048;                                          \
  unsigned xw_ = (unsigned)(arow & 7) << 4;                                \
  _Pragma("unroll 4")                                                      \
  for (int j = 0; j < 8; ++j) {                                            \
    f32x4 va_ = __builtin_nontemporal_load((const f32x4*)(sr_ + j * 128)); \
    f32x4 vb_ = __builtin_nontemporal_load((const f32x4*)(sr_ + j * 128 + 4)); \
    uint4 o_;                                                              \
    o_.x = pk2(va_[0], va_[1]); o_.y = pk2(va_[2], va_[3]);                \
    o_.z = pk2(vb_[0], vb_[1]); o_.w = pk2(vb_[2], vb_[3]);                \
    unsigned kb_ = ((unsigned)(acol * 16 + j * 256)) ^ xw_;                \
    *(uint4*)(lw_ + kb_) = o_;                                             \
  }                                                                        \
} while (0)

#define HALF_LOOP(KT0) do {                                                \
  const ushort* bp_ = Bmain + (size_t)(KT0) * 32768 + boff;                \
  bf16x8 bfA_[4], bfB_[4];                                                 \
  _Pragma("unroll")                                                        \
  for (int nf = 0; nf < 4; ++nf)                                           \
    bfA_[nf] = *(const bf16x8*)(bp_ + nf * 512);                           \
  _Pragma("unroll 1")                                                      \
  for (int kt = 0; kt < 32; kt += 2) {                                     \
    _Pragma("unroll")                                                      \
    for (int nf = 0; nf < 4; ++nf)                                         \
      bfB_[nf] = *(const bf16x8*)(bp_ + (size_t)(kt + 1) * 32768 + nf * 512); \
    {                                                                      \
      unsigned ko_ = ((unsigned)(kt << 6) + lh16) ^ xr;                    \
      const char* ab_ = abase + ko_;                                       \
      bf16x8 af_[4];                                                       \
      _Pragma("unroll")                                                    \
      for (int mf = 0; mf < 4; ++mf)                                       \
        af_[mf] = *(const bf16x8*)(ab_ + mf * 32768);                      \
      _Pragma("unroll")                                                    \
      for (int nf = 0; nf < 4; ++nf)                                       \
        _Pragma("unroll")                                                  \
        for (int mf = 0; mf < 4; ++mf)                                     \
          acc[mf][nf] = __builtin_amdgcn_mfma_f32_16x16x32_bf16(           \
              af_[mf], bfA_[nf], acc[mf][nf], 0, 0, 0);                    \
    }                                                                      \
    _Pragma("unroll")                                                      \
    for (int nf = 0; nf < 4; ++nf)  /* kt=30: over-read -> Bk1, benign */  \
      bfA_[nf] = *(const bf16x8*)(bp_ + (size_t)(kt + 2) * 32768 + nf * 512); \
    {                                                                      \
      unsigned ko_ = ((unsigned)((kt + 1) << 6) + lh16) ^ xr;              \
      const char* ab_ = abase + ko_;                                       \
      bf16x8 af_[4];                                                       \
      _Pragma("unroll")                                                    \
      for (int mf = 0; mf < 4; ++mf)                                       \
        af_[mf] = *(const bf16x8*)(ab_ + mf * 32768);                      \
      _Pragma("unroll")                                                    \
      for (int nf = 0; nf < 4; ++nf)                                       \
        _Pragma("unroll")                                                  \
        for (int mf = 0; mf < 4; ++mf)                                     \
          acc[mf][nf] = __builtin_amdgcn_mfma_f32_16x16x32_bf16(           \
              af_[mf], bfB_[nf], acc[mf][nf], 0, 0, 0);                    \
    }                                                                      \
  }                                                                        \
} while (0)

__global__ __launch_bounds__(1024) void main_kernel(
    const float* __restrict__ routed, const float* __restrict__ delta,
    const float* __restrict__ simrow, const ushort* __restrict__ Bmain,
    const float* __restrict__ tpart, const float* __restrict__ gamma,
    const float* __restrict__ beta, float* __restrict__ out_arg,
    ushort* __restrict__ argb) {
  extern __shared__ char smem[];
  // [0,131072): Abig 64 rows x 2048B (one K-half, bf16, XOR-swizzled)
  // [131072,131328): ldsW
  // epilogue overlay: lnS [0,4096), lnQ [4096,8192)
  float* ldsW = (float*)(smem + 131072);
  float* lnS = (float*)smem;
  float* lnQ = (float*)(smem + 4096);

  int tid = threadIdx.x, l = tid & 63, wid = tid >> 6;   // wid 0..15
  int bx = blockIdx.x;                  // tokens bx*4 .. bx*4+3
  int lr = l & 15, lh = l >> 4;

  if (tid < 4) {                        // softmax over K=16 for token bx*4+tid
    int n = bx * 4 + tid;
    float sv[16], mx = -1e30f;
#pragma unroll
    for (int j = 0; j < 16; ++j) { sv[j] = simrow[n * 16 + j]; mx = fmaxf(mx, sv[j]); }
    float s = 0.f;
#pragma unroll
    for (int j = 0; j < 16; ++j) { sv[j] = expf(sv[j] - mx); s += sv[j]; }
    float inv = 1.0f / s;
#pragma unroll
    for (int j = 0; j < 16; ++j) ldsW[tid * 16 + j] = sv[j] * inv;
  }

  // staging geometry: thread covers row arow; per j, 8 f32 at elem
  // acol*8 + j*128 -> 16B bf16 at logical byte acol*16 + j*256 (swizzled)
  const int arow = tid >> 4;            // 0..63
  const int acol = tid & 15;            // 0..15

  // A-read addressing: row = mf*16 + lr; byte = row*2048 + ((kt*64+lh*16)^xr)
  // xr = (row&7)<<4 = (lr&7)<<4 (mf*16 = 0 mod 8) -> mf folds to +32768*mf
  const unsigned xr = (unsigned)(lr & 7) << 4;
  const unsigned lh16 = (unsigned)lh * 16;
  const char* abase = smem + lr * 2048;

  // B per-lane offset (packed layout, unchanged)
  const size_t boff = (size_t)(wid >> 1) * 4096 + (size_t)(wid & 1) * 2048 +
                      (size_t)l * 8;

  f32x4 acc[4][4] = {};

  STAGE_HALF(routed);
  __syncthreads();
  HALF_LOOP(0);
  __syncthreads();                       // all reads of half 0 done
  STAGE_HALF(delta);
  __syncthreads();
  HALF_LOOP(32);
  __syncthreads();                       // reads done -> lnS/lnQ may overlay

  // ---- fused epilogue (green R16; fast GELU, tpart NT) ----
  const float inv_d = 1.0f / 1024.0f;
  float gam[4], bet[4];
#pragma unroll
  for (int nf = 0; nf < 4; ++nf) {
    int c = wid * 64 + nf * 16 + lr;
    gam[nf] = gamma[c]; bet[nf] = beta[c];
  }
#pragma unroll
  for (int mf = 0; mf < 4; ++mf) {
    int tokrow = bx * 4 + mf;
    float s[4] = {0, 0, 0, 0}, q[4] = {0, 0, 0, 0};
#pragma unroll
    for (int nf = 0; nf < 4; ++nf) {
      float tp = __builtin_nontemporal_load(
          tpart + (size_t)tokrow * 1024 + wid * 64 + nf * 16 + lr);
#pragma unroll
      for (int j = 0; j < 4; ++j) {
        float h = acc[mf][nf][j] + tp;
        float u = h * (1.5957691f + 0.07135481f * h * h);
        float g = h / (1.0f + __expf(-u));
        acc[mf][nf][j] = g;
        s[j] += g; q[j] += g * g;
      }
    }
#pragma unroll
    for (int j = 0; j < 4; ++j) {
#pragma unroll
      for (int d = 1; d <= 8; d <<= 1) {
        s[j] += __shfl_xor(s[j], d, 64);
        q[j] += __shfl_xor(q[j], d, 64);
      }
    }
    if (lr == 0) {
#pragma unroll
      for (int j = 0; j < 4; ++j) {
        int row = mf * 16 + lh * 4 + j;
        lnS[row * 16 + wid] = s[j];
        lnQ[row * 16 + wid] = q[j];
      }
    }
  }
  __syncthreads();
#pragma unroll
  for (int mf = 0; mf < 4; ++mf) {
    float mu[4], rs[4], wk[4];
#pragma unroll
    for (int j = 0; j < 4; ++j) {
      int row = mf * 16 + lh * 4 + j;
      float S = 0.f, Q = 0.f;
#pragma unroll
      for (int w4 = 0; w4 < 4; ++w4) {
        f32x4 vs = *(const f32x4*)&lnS[row * 16 + w4 * 4];
        f32x4 vq = *(const f32x4*)&lnQ[row * 16 + w4 * 4];
        S += vs[0] + vs[1] + vs[2] + vs[3];
        Q += vq[0] + vq[1] + vq[2] + vq[3];
      }
      float m_ = S * inv_d;
      mu[j] = m_;
      rs[j] = rsqrtf(Q * inv_d - m_ * m_ + 1e-5f);
      wk[j] = ldsW[row];
    }
#pragma unroll
    for (int nf = 0; nf < 4; ++nf) {
      float ws = 0.f;
#pragma unroll
      for (int j = 0; j < 4; ++j) {
        float y = (acc[mf][nf][j] - mu[j]) * rs[j] * gam[nf] + bet[nf];
        ws += wk[j] * y;
      }
      ws += __shfl_xor(ws, 16, 64);
      ws += __shfl_xor(ws, 32, 64);
      if (lh == 0) {
        size_t oidx = (size_t)(bx * 4 + mf) * 1024 + wid * 64 + nf * 16 + lr;
        out_arg[oidx] = ws;
        argb[oidx] = f2bf(ws);
      }
    }
  }
}

// ---------------------------------------------------------------------------
extern "C" void kernel_launch(void* const* d_in, const int* in_sizes, int n_in,
                              void* d_out, int out_size, void* d_ws, size_t ws_size,
                              hipStream_t stream) {
  const float* token  = (const float*)d_in[0];
  const float* routed = (const float*)d_in[1];
  const float* simrow = (const float*)d_in[2];
  const float* delta  = (const float*)d_in[3];
  const float* Wl     = (const float*)d_in[4];
  const float* bl     = (const float*)d_in[5];
  const float* gamma  = (const float*)d_in[6];
  const float* beta   = (const float*)d_in[7];
  const float* Wg     = (const float*)d_in[8];
  const float* bg     = (const float*)d_in[9];

  char* ws = (char*)d_ws;
  ushort* Bmain  = (ushort*)(ws);                        // 4 MB
  ushort* Bk1    = (ushort*)(ws + (4u << 20));           // 2 MB
  ushort* Bgate  = (ushort*)(ws + (6u << 20));           // 4 MB
  float*  tpart  = (float*)(ws + (10u << 20));           // 16 MB
  ushort* tokenb = (ushort*)(ws + (26u << 20));          // 8 MB
  ushort* argb   = (ushort*)(ws + (34u << 20));          // 8 MB (total 42 MB)

  float* out_arg  = (float*)d_out;
  float* out_gate = out_arg + (size_t)4096 * 1024;

  const int SMEM = 131328;   // Abig 128K | ldsW 256B
  hipFuncSetAttribute(reinterpret_cast<const void*>(main_kernel),
                      hipFuncAttributeMaxDynamicSharedMemorySize, SMEM);

  prep_kernel<<<1536, 256, 0, stream>>>(Wl, Wg, token, Bmain, Bk1, Bgate, tokenb);
  gemm_small_b<32, 32, 0><<<dim3(64, 8), 256, 0, stream>>>(
      tokenb, tokenb, Bk1, bl, tpart);
  main_kernel<<<1024, 1024, SMEM, stream>>>(
      routed, delta, simrow, Bmain, tpart, gamma, beta, out_arg, argb);
  gemm_small_b<64, 32, 1><<<dim3(64, 8), 256, 0, stream>>>(
      tokenb, argb, Bgate, bg, out_gate);
}

// Round 19
// 475.241 us; speedup vs baseline: 1.5589x; 1.0022x over previous
//
#include <hip/hip_runtime.h>
#include <hip/hip_bf16.h>

// Problem constants: D=1024, N=4096, K=16, M = N*K = 65536, K-dim main = 2048

typedef __attribute__((ext_vector_type(4))) float f32x4;
typedef __attribute__((ext_vector_type(2))) float f32x2;
typedef __attribute__((ext_vector_type(8))) short bf16x8;

__device__ __forceinline__ ushort f2bf(float f) {
  unsigned b = __builtin_bit_cast(unsigned, f);
  b += 0x7FFFu + ((b >> 16) & 1u);   // RNE
  return (ushort)(b >> 16);
}
__device__ __forceinline__ unsigned pk2(float a, float b) {
  return (unsigned)f2bf(a) | ((unsigned)f2bf(b) << 16);
}

// In-tile XOR swizzle for 4KB [64 rows][64B] A tiles (R16-verified: lower
// measured bank conflicts than the whole-half row swizzle, 9.4M vs 26M).
__device__ __forceinline__ unsigned swz(unsigned a) {
  return a ^ (((a >> 7) & 3u) << 4);
}

// ---------------------------------------------------------------------------
// prep: LDS tile-transpose weight packer (verified green R4-R18) + mode 3
// token f32 -> bf16 (RNE, bit-identical to per-load cvt).
// ---------------------------------------------------------------------------
__global__ __launch_bounds__(256) void prep_kernel(
    const float* __restrict__ Wl, const float* __restrict__ Wg,
    const float* __restrict__ token,
    ushort* __restrict__ Bmain, ushort* __restrict__ Bk1,
    ushort* __restrict__ Bgate, ushort* __restrict__ tokenb) {
  int t = threadIdx.x;
  int bid = blockIdx.x;
  if (bid >= 1280) {                    // mode 3: token -> bf16
    size_t base = (size_t)(bid - 1280) * 16384;
#pragma unroll
    for (int it = 0; it < 16; ++it) {
      size_t e = base + (size_t)it * 1024 + t * 4;
      f32x4 v = *(const f32x4*)(token + e);
      uint2 o; o.x = pk2(v[0], v[1]); o.y = pk2(v[2], v[3]);
      *(uint2*)(tokenb + e) = o;
    }
    return;
  }
  __shared__ float L[32][129];
  const float* src; int row0, mode, kt, wg; ushort* dst;
  if (bid < 512)      { mode = 0; kt = bid >> 3;        wg = bid & 7; src = Wl; row0 = 1024 + kt * 32; dst = Bmain; }
  else if (bid < 768) { mode = 1; kt = (bid - 512) >> 3; wg = (bid - 512) & 7; src = Wl; row0 = kt * 32; dst = Bk1; }
  else                { mode = 2; kt = (bid - 768) >> 3; wg = (bid - 768) & 7; src = Wg; row0 = kt * 32; dst = Bgate; }
  int col0 = wg * 128;
  bool dosum = (mode == 2) && (kt >= 32);
#pragma unroll
  for (int p = 0; p < 4; ++p) {
    int r = p * 8 + (t >> 5), c = (t & 31) * 4;
    const float* sp = src + (size_t)(row0 + r) * 1024 + col0 + c;
    f32x4 v = *(const f32x4*)sp;
    if (dosum) { f32x4 v2 = *(const f32x4*)(sp + (size_t)1024 * 1024); v += v2; }
    L[r][c] = v[0]; L[r][c + 1] = v[1]; L[r][c + 2] = v[2]; L[r][c + 3] = v[3];
  }
  __syncthreads();
  if (mode == 0) {
    for (int c = t; c < 512; c += 256) {
      int nf = c >> 6, lane = c & 63, lr_ = lane & 15, lh_ = lane >> 4;
      bf16x8 o;
#pragma unroll
      for (int m = 0; m < 8; ++m) o[m] = (short)f2bf(L[lh_ * 8 + m][nf * 16 + lr_]);
      *(bf16x8*)(dst + (size_t)kt * 32768 + wg * 4096 + c * 8) = o;
    }
  } else {
    for (int c = t; c < 512; c += 256) {
      int nn = c >> 2, q = c & 3;
      bf16x8 o;
#pragma unroll
      for (int m = 0; m < 8; ++m) o[m] = (short)f2bf(L[q * 8 + m][nn]);
      *(bf16x8*)(dst + (size_t)kt * 32768 + (size_t)(wg * 128 + nn) * 32 + q * 8) = o;
    }
  }
}

// ---------------------------------------------------------------------------
// gemm_small_b: C = act(A_bf16 @ Bpack + bias). 64x128 tile, 4 waves (2x2),
// wave tile 32x64, grid (M/64, 8). (green R16/R18)
// ---------------------------------------------------------------------------
template <int NKT, int NSPLIT, int ACT>
__global__ __launch_bounds__(256) void gemm_small_b(
    const ushort* __restrict__ A0, const ushort* __restrict__ A1,
    const ushort* __restrict__ Bp, const float* __restrict__ bias,
    float* __restrict__ Cout) {
  int tid = threadIdx.x, l = tid & 63, wid = tid >> 6;
  int wm = wid & 1, wn = wid >> 1;
  int mbase = blockIdx.x * 64 + wm * 32;
  int nbase = blockIdx.y * 128 + wn * 64;
  int lr = l & 15, lh = l >> 4;
  f32x4 acc[2][4] = {};
#pragma unroll 1
  for (int kt = 0; kt < NKT; ++kt) {
    const ushort* As = (kt < NSPLIT) ? A0 : A1;
    int ke = ((kt < NSPLIT) ? kt : kt - NSPLIT) * 32 + lh * 8;
    bf16x8 af[2];
#pragma unroll
    for (int mf = 0; mf < 2; ++mf)
      af[mf] = *(const bf16x8*)(As + (size_t)(mbase + mf * 16 + lr) * 1024 + ke);
    bf16x8 bf[4];
#pragma unroll
    for (int nf = 0; nf < 4; ++nf)
      bf[nf] = *(const bf16x8*)(Bp + (size_t)kt * 32768 +
                                (size_t)(nbase + nf * 16 + lr) * 32 + lh * 8);
#pragma unroll
    for (int nf = 0; nf < 4; ++nf)
#pragma unroll
      for (int mf = 0; mf < 2; ++mf)
        acc[mf][nf] = __builtin_amdgcn_mfma_f32_16x16x32_bf16(
            af[mf], bf[nf], acc[mf][nf], 0, 0, 0);
  }
#pragma unroll
  for (int nf = 0; nf < 4; ++nf) {
    int col = nbase + nf * 16 + lr;
    float bs = bias[col];
#pragma unroll
    for (int mf = 0; mf < 2; ++mf)
#pragma unroll
      for (int j = 0; j < 4; ++j) {
        int row = mbase + mf * 16 + lh * 4 + j;
        float v = acc[mf][nf][j] + bs;
        if (ACT == 1) v = 1.0f / (1.0f + expf(-v));
        Cout[(size_t)row * 1024 + col] = v;
      }
  }
}

// ---------------------------------------------------------------------------
// main fused kernel — barrier-free K-loop (green R18) with the A-half stored
// as 32 PER-KT 4KB TILES (tile kt at kt*4096, in-tile R16 swizzle) instead
// of whole-half rows: R18's row layout measured 26.2M LDS bank-conflict
// cycles vs R16's 9.4M — this restores the verified lower-conflict layout
// inside the barrier-free structure. Staging coverage: thread (arow,acol)
// writes chunk j to tile j*4+(acol>>2), in-tile byte swz(arow*64+(acol&3)*16)
// (4 acol x 64 arow per tile = 4KB complete). Reads: smem + kt*4096 + aoff0
// + mf*1024, aoff0 = swz(lr*64+lh*16) (XOR key = lr bits 1,2; mf-invariant).
// Everything else byte-identical to green R18.
// ---------------------------------------------------------------------------
#define STAGE_HALF(SRC) do {                                               \
  const float* sr_ = (SRC) + (size_t)(bx * 64 + arow) * 1024 + acol * 8;   \
  _Pragma("unroll 4")                                                      \
  for (int j = 0; j < 8; ++j) {                                            \
    f32x4 va_ = __builtin_nontemporal_load((const f32x4*)(sr_ + j * 128)); \
    f32x4 vb_ = __builtin_nontemporal_load((const f32x4*)(sr_ + j * 128 + 4)); \
    uint4 o_;                                                              \
    o_.x = pk2(va_[0], va_[1]); o_.y = pk2(va_[2], va_[3]);                \
    o_.z = pk2(vb_[0], vb_[1]); o_.w = pk2(vb_[2], vb_[3]);                \
    int kt_ = j * 4 + (acol >> 2);                                         \
    unsigned ib_ = swz((unsigned)(arow * 64 + (acol & 3) * 16));           \
    *(uint4*)(smem + kt_ * 4096 + ib_) = o_;                               \
  }                                                                        \
} while (0)

#define HALF_LOOP(KT0) do {                                                \
  const ushort* bp_ = Bmain + (size_t)(KT0) * 32768 + boff;                \
  bf16x8 bfA_[4], bfB_[4];                                                 \
  _Pragma("unroll")                                                        \
  for (int nf = 0; nf < 4; ++nf)                                           \
    bfA_[nf] = *(const bf16x8*)(bp_ + nf * 512);                           \
  _Pragma("unroll 1")                                                      \
  for (int kt = 0; kt < 32; kt += 2) {                                     \
    _Pragma("unroll")                                                      \
    for (int nf = 0; nf < 4; ++nf)                                         \
      bfB_[nf] = *(const bf16x8*)(bp_ + (size_t)(kt + 1) * 32768 + nf * 512); \
    {                                                                      \
      const char* ab_ = abase + (unsigned)(kt << 12);                      \
      bf16x8 af_[4];                                                       \
      _Pragma("unroll")                                                    \
      for (int mf = 0; mf < 4; ++mf)                                       \
        af_[mf] = *(const bf16x8*)(ab_ + mf * 1024);                       \
      _Pragma("unroll")                                                    \
      for (int nf = 0; nf < 4; ++nf)                                       \
        _Pragma("unroll")                                                  \
        for (int mf = 0; mf < 4; ++mf)                                     \
          acc[mf][nf] = __builtin_amdgcn_mfma_f32_16x16x32_bf16(           \
              af_[mf], bfA_[nf], acc[mf][nf], 0, 0, 0);                    \
    }                                                                      \
    _Pragma("unroll")                                                      \
    for (int nf = 0; nf < 4; ++nf)  /* kt=30: over-read -> Bk1, benign */  \
      bfA_[nf] = *(const bf16x8*)(bp_ + (size_t)(kt + 2) * 32768 + nf * 512); \
    {                                                                      \
      const char* ab_ = abase + (unsigned)((kt + 1) << 12);                \
      bf16x8 af_[4];                                                       \
      _Pragma("unroll")                                                    \
      for (int mf = 0; mf < 4; ++mf)                                       \
        af_[mf] = *(const bf16x8*)(ab_ + mf * 1024);                       \
      _Pragma("unroll")                                                    \
      for (int nf = 0; nf < 4; ++nf)                                       \
        _Pragma("unroll")                                                  \
        for (int mf = 0; mf < 4; ++mf)                                     \
          acc[mf][nf] = __builtin_amdgcn_mfma_f32_16x16x32_bf16(           \
              af_[mf], bfB_[nf], acc[mf][nf], 0, 0, 0);                    \
    }                                                                      \
  }                                                                        \
} while (0)

__global__ __launch_bounds__(1024) void main_kernel(
    const float* __restrict__ routed, const float* __restrict__ delta,
    const float* __restrict__ simrow, const ushort* __restrict__ Bmain,
    const float* __restrict__ tpart, const float* __restrict__ gamma,
    const float* __restrict__ beta, float* __restrict__ out_arg,
    ushort* __restrict__ argb) {
  extern __shared__ char smem[];
  // [0,131072): 32 per-kt A tiles x 4KB (one K-half, bf16, in-tile swizzle)
  // [131072,131328): ldsW
  // epilogue overlay: lnS [0,4096), lnQ [4096,8192)
  float* ldsW = (float*)(smem + 131072);
  float* lnS = (float*)smem;
  float* lnQ = (float*)(smem + 4096);

  int tid = threadIdx.x, l = tid & 63, wid = tid >> 6;   // wid 0..15
  int bx = blockIdx.x;                  // tokens bx*4 .. bx*4+3
  int lr = l & 15, lh = l >> 4;

  if (tid < 4) {                        // softmax over K=16 for token bx*4+tid
    int n = bx * 4 + tid;
    float sv[16], mx = -1e30f;
#pragma unroll
    for (int j = 0; j < 16; ++j) { sv[j] = simrow[n * 16 + j]; mx = fmaxf(mx, sv[j]); }
    float s = 0.f;
#pragma unroll
    for (int j = 0; j < 16; ++j) { sv[j] = expf(sv[j] - mx); s += sv[j]; }
    float inv = 1.0f / s;
#pragma unroll
    for (int j = 0; j < 16; ++j) ldsW[tid * 16 + j] = sv[j] * inv;
  }

  // staging geometry: thread covers row arow; per j, 8 f32 at elem
  // acol*8 + j*128 -> tile j*4+(acol>>2), in-tile byte (arow,(acol&3)*16)
  const int arow = tid >> 4;            // 0..63
  const int acol = tid & 15;            // 0..15

  // A-read addressing: tile kt, in-tile byte swz((mf*16+lr)*64 + lh*16);
  // swz's XOR key = bits 7,8 = lr bits 1,2 (mf-invariant; mf folds to +1024*mf)
  const unsigned aoff0 = swz((unsigned)(lr * 64 + lh * 16));
  const char* abase = smem + aoff0;

  // B per-lane offset (packed layout, unchanged)
  const size_t boff = (size_t)(wid >> 1) * 4096 + (size_t)(wid & 1) * 2048 +
                      (size_t)l * 8;

  f32x4 acc[4][4] = {};

  STAGE_HALF(routed);
  __syncthreads();
  HALF_LOOP(0);
  __syncthreads();                       // all reads of half 0 done
  STAGE_HALF(delta);
  __syncthreads();
  HALF_LOOP(32);
  __syncthreads();                       // reads done -> lnS/lnQ may overlay

  // ---- fused epilogue (green R16/R18; fast GELU, tpart NT) ----
  const float inv_d = 1.0f / 1024.0f;
  float gam[4], bet[4];
#pragma unroll
  for (int nf = 0; nf < 4; ++nf) {
    int c = wid * 64 + nf * 16 + lr;
    gam[nf] = gamma[c]; bet[nf] = beta[c];
  }
#pragma unroll
  for (int mf = 0; mf < 4; ++mf) {
    int tokrow = bx * 4 + mf;
    float s[4] = {0, 0, 0, 0}, q[4] = {0, 0, 0, 0};
#pragma unroll
    for (int nf = 0; nf < 4; ++nf) {
      float tp = __builtin_nontemporal_load(
          tpart + (size_t)tokrow * 1024 + wid * 64 + nf * 16 + lr);
#pragma unroll
      for (int j = 0; j < 4; ++j) {
        float h = acc[mf][nf][j] + tp;
        float u = h * (1.5957691f + 0.07135481f * h * h);
        float g = h / (1.0f + __expf(-u));
        acc[mf][nf][j] = g;
        s[j] += g; q[j] += g * g;
      }
    }
#pragma unroll
    for (int j = 0; j < 4; ++j) {
#pragma unroll
      for (int d = 1; d <= 8; d <<= 1) {
        s[j] += __shfl_xor(s[j], d, 64);
        q[j] += __shfl_xor(q[j], d, 64);
      }
    }
    if (lr == 0) {
#pragma unroll
      for (int j = 0; j < 4; ++j) {
        int row = mf * 16 + lh * 4 + j;
        lnS[row * 16 + wid] = s[j];
        lnQ[row * 16 + wid] = q[j];
      }
    }
  }
  __syncthreads();
#pragma unroll
  for (int mf = 0; mf < 4; ++mf) {
    float mu[4], rs[4], wk[4];
#pragma unroll
    for (int j = 0; j < 4; ++j) {
      int row = mf * 16 + lh * 4 + j;
      float S = 0.f, Q = 0.f;
#pragma unroll
      for (int w4 = 0; w4 < 4; ++w4) {
        f32x4 vs = *(const f32x4*)&lnS[row * 16 + w4 * 4];
        f32x4 vq = *(const f32x4*)&lnQ[row * 16 + w4 * 4];
        S += vs[0] + vs[1] + vs[2] + vs[3];
        Q += vq[0] + vq[1] + vq[2] + vq[3];
      }
      float m_ = S * inv_d;
      mu[j] = m_;
      rs[j] = rsqrtf(Q * inv_d - m_ * m_ + 1e-5f);
      wk[j] = ldsW[row];
    }
#pragma unroll
    for (int nf = 0; nf < 4; ++nf) {
      float ws = 0.f;
#pragma unroll
      for (int j = 0; j < 4; ++j) {
        float y = (acc[mf][nf][j] - mu[j]) * rs[j] * gam[nf] + bet[nf];
        ws += wk[j] * y;
      }
      ws += __shfl_xor(ws, 16, 64);
      ws += __shfl_xor(ws, 32, 64);
      if (lh == 0) {
        size_t oidx = (size_t)(bx * 4 + mf) * 1024 + wid * 64 + nf * 16 + lr;
        out_arg[oidx] = ws;
        argb[oidx] = f2bf(ws);
      }
    }
  }
}

// ---------------------------------------------------------------------------
extern "C" void kernel_launch(void* const* d_in, const int* in_sizes, int n_in,
                              void* d_out, int out_size, void* d_ws, size_t ws_size,
                              hipStream_t stream) {
  const float* token  = (const float*)d_in[0];
  const float* routed = (const float*)d_in[1];
  const float* simrow = (const float*)d_in[2];
  const float* delta  = (const float*)d_in[3];
  const float* Wl     = (const float*)d_in[4];
  const float* bl     = (const float*)d_in[5];
  const float* gamma  = (const float*)d_in[6];
  const float* beta   = (const float*)d_in[7];
  const float* Wg     = (const float*)d_in[8];
  const float* bg     = (const float*)d_in[9];

  char* ws = (char*)d_ws;
  ushort* Bmain  = (ushort*)(ws);                        // 4 MB
  ushort* Bk1    = (ushort*)(ws + (4u << 20));           // 2 MB
  ushort* Bgate  = (ushort*)(ws + (6u << 20));           // 4 MB
  float*  tpart  = (float*)(ws + (10u << 20));           // 16 MB
  ushort* tokenb = (ushort*)(ws + (26u << 20));          // 8 MB
  ushort* argb   = (ushort*)(ws + (34u << 20));          // 8 MB (total 42 MB)

  float* out_arg  = (float*)d_out;
  float* out_gate = out_arg + (size_t)4096 * 1024;

  const int SMEM = 131328;   // 32 A tiles 128K | ldsW 256B
  hipFuncSetAttribute(reinterpret_cast<const void*>(main_kernel),
                      hipFuncAttributeMaxDynamicSharedMemorySize, SMEM);

  prep_kernel<<<1536, 256, 0, stream>>>(Wl, Wg, token, Bmain, Bk1, Bgate, tokenb);
  gemm_small_b<32, 32, 0><<<dim3(64, 8), 256, 0, stream>>>(
      tokenb, tokenb, Bk1, bl, tpart);
  main_kernel<<<1024, 1024, SMEM, stream>>>(
      routed, delta, simrow, Bmain, tpart, gamma, beta, out_arg, argb);
  gemm_small_b<64, 32, 1><<<dim3(64, 8), 256, 0, stream>>>(
      tokenb, argb, Bgate, bg, out_gate);
}

// Round 20
// 469.793 us; speedup vs baseline: 1.5770x; 1.0116x over previous
//
#include <hip/hip_runtime.h>
#include <hip/hip_bf16.h>

// Problem constants: D=1024, N=4096, K=16, M = N*K = 65536, K-dim main = 2048

typedef __attribute__((ext_vector_type(4))) float f32x4;
typedef __attribute__((ext_vector_type(2))) float f32x2;
typedef __attribute__((ext_vector_type(8))) short bf16x8;

__device__ __forceinline__ ushort f2bf(float f) {
  unsigned b = __builtin_bit_cast(unsigned, f);
  b += 0x7FFFu + ((b >> 16) & 1u);   // RNE
  return (ushort)(b >> 16);
}
__device__ __forceinline__ unsigned pk2(float a, float b) {
  return (unsigned)f2bf(a) | ((unsigned)f2bf(b) << 16);
}

// In-tile XOR swizzle for 4KB [64 rows][64B] A tiles (R16/R19-verified)
__device__ __forceinline__ unsigned swz(unsigned a) {
  return a ^ (((a >> 7) & 3u) << 4);
}

// ---------------------------------------------------------------------------
// prep: LDS tile-transpose weight packer (verified green R4-R19) + mode 3
// token f32 -> bf16 (RNE, bit-identical to per-load cvt).
// ---------------------------------------------------------------------------
__global__ __launch_bounds__(256) void prep_kernel(
    const float* __restrict__ Wl, const float* __restrict__ Wg,
    const float* __restrict__ token,
    ushort* __restrict__ Bmain, ushort* __restrict__ Bk1,
    ushort* __restrict__ Bgate, ushort* __restrict__ tokenb) {
  int t = threadIdx.x;
  int bid = blockIdx.x;
  if (bid >= 1280) {                    // mode 3: token -> bf16
    size_t base = (size_t)(bid - 1280) * 16384;
#pragma unroll
    for (int it = 0; it < 16; ++it) {
      size_t e = base + (size_t)it * 1024 + t * 4;
      f32x4 v = *(const f32x4*)(token + e);
      uint2 o; o.x = pk2(v[0], v[1]); o.y = pk2(v[2], v[3]);
      *(uint2*)(tokenb + e) = o;
    }
    return;
  }
  __shared__ float L[32][129];
  const float* src; int row0, mode, kt, wg; ushort* dst;
  if (bid < 512)      { mode = 0; kt = bid >> 3;        wg = bid & 7; src = Wl; row0 = 1024 + kt * 32; dst = Bmain; }
  else if (bid < 768) { mode = 1; kt = (bid - 512) >> 3; wg = (bid - 512) & 7; src = Wl; row0 = kt * 32; dst = Bk1; }
  else                { mode = 2; kt = (bid - 768) >> 3; wg = (bid - 768) & 7; src = Wg; row0 = kt * 32; dst = Bgate; }
  int col0 = wg * 128;
  bool dosum = (mode == 2) && (kt >= 32);
#pragma unroll
  for (int p = 0; p < 4; ++p) {
    int r = p * 8 + (t >> 5), c = (t & 31) * 4;
    const float* sp = src + (size_t)(row0 + r) * 1024 + col0 + c;
    f32x4 v = *(const f32x4*)sp;
    if (dosum) { f32x4 v2 = *(const f32x4*)(sp + (size_t)1024 * 1024); v += v2; }
    L[r][c] = v[0]; L[r][c + 1] = v[1]; L[r][c + 2] = v[2]; L[r][c + 3] = v[3];
  }
  __syncthreads();
  if (mode == 0) {
    for (int c = t; c < 512; c += 256) {
      int nf = c >> 6, lane = c & 63, lr_ = lane & 15, lh_ = lane >> 4;
      bf16x8 o;
#pragma unroll
      for (int m = 0; m < 8; ++m) o[m] = (short)f2bf(L[lh_ * 8 + m][nf * 16 + lr_]);
      *(bf16x8*)(dst + (size_t)kt * 32768 + wg * 4096 + c * 8) = o;
    }
  } else {
    for (int c = t; c < 512; c += 256) {
      int nn = c >> 2, q = c & 3;
      bf16x8 o;
#pragma unroll
      for (int m = 0; m < 8; ++m) o[m] = (short)f2bf(L[q * 8 + m][nn]);
      *(bf16x8*)(dst + (size_t)kt * 32768 + (size_t)(wg * 128 + nn) * 32 + q * 8) = o;
    }
  }
}

// ---------------------------------------------------------------------------
// gemm_small_b: C = act(A_bf16 @ Bpack + bias). 64x128 tile, 4 waves (2x2),
// wave tile 32x64, grid (M/64, 8). (green R16-R19)
// Output stores NON-TEMPORAL: tpart is read once (NT) by main; out_gate is
// never re-read — both were streaming through L2 and evicting the hot B
// working sets.
// ---------------------------------------------------------------------------
template <int NKT, int NSPLIT, int ACT>
__global__ __launch_bounds__(256) void gemm_small_b(
    const ushort* __restrict__ A0, const ushort* __restrict__ A1,
    const ushort* __restrict__ Bp, const float* __restrict__ bias,
    float* __restrict__ Cout) {
  int tid = threadIdx.x, l = tid & 63, wid = tid >> 6;
  int wm = wid & 1, wn = wid >> 1;
  int mbase = blockIdx.x * 64 + wm * 32;
  int nbase = blockIdx.y * 128 + wn * 64;
  int lr = l & 15, lh = l >> 4;
  f32x4 acc[2][4] = {};
#pragma unroll 1
  for (int kt = 0; kt < NKT; ++kt) {
    const ushort* As = (kt < NSPLIT) ? A0 : A1;
    int ke = ((kt < NSPLIT) ? kt : kt - NSPLIT) * 32 + lh * 8;
    bf16x8 af[2];
#pragma unroll
    for (int mf = 0; mf < 2; ++mf)
      af[mf] = *(const bf16x8*)(As + (size_t)(mbase + mf * 16 + lr) * 1024 + ke);
    bf16x8 bf[4];
#pragma unroll
    for (int nf = 0; nf < 4; ++nf)
      bf[nf] = *(const bf16x8*)(Bp + (size_t)kt * 32768 +
                                (size_t)(nbase + nf * 16 + lr) * 32 + lh * 8);
#pragma unroll
    for (int nf = 0; nf < 4; ++nf)
#pragma unroll
      for (int mf = 0; mf < 2; ++mf)
        acc[mf][nf] = __builtin_amdgcn_mfma_f32_16x16x32_bf16(
            af[mf], bf[nf], acc[mf][nf], 0, 0, 0);
  }
#pragma unroll
  for (int nf = 0; nf < 4; ++nf) {
    int col = nbase + nf * 16 + lr;
    float bs = bias[col];
#pragma unroll
    for (int mf = 0; mf < 2; ++mf)
#pragma unroll
      for (int j = 0; j < 4; ++j) {
        int row = mbase + mf * 16 + lh * 4 + j;
        float v = acc[mf][nf][j] + bs;
        if (ACT == 1) v = 1.0f / (1.0f + expf(-v));
        __builtin_nontemporal_store(v, &Cout[(size_t)row * 1024 + col]);
      }
  }
}

// ---------------------------------------------------------------------------
// main fused kernel — green R19 (barrier-free K-loop, 32 per-kt 4KB A tiles,
// in-tile swizzle) + two zero-register tweaks:
//  (1) s_setprio(1) around each 16-MFMA cluster (T5: pays when waves have
//      role diversity — true in the barrier-free drifted loop).
//  (2) out_arg stored NON-TEMPORAL (never re-read on device; its stream was
//      evicting Bmain from L2 — B in-flight depth is register/LDS-capped at
//      64KB/CU, so B L2-residency is the only latency lever left).
// ---------------------------------------------------------------------------
#define STAGE_HALF(SRC) do {                                               \
  const float* sr_ = (SRC) + (size_t)(bx * 64 + arow) * 1024 + acol * 8;   \
  _Pragma("unroll 4")                                                      \
  for (int j = 0; j < 8; ++j) {                                            \
    f32x4 va_ = __builtin_nontemporal_load((const f32x4*)(sr_ + j * 128)); \
    f32x4 vb_ = __builtin_nontemporal_load((const f32x4*)(sr_ + j * 128 + 4)); \
    uint4 o_;                                                              \
    o_.x = pk2(va_[0], va_[1]); o_.y = pk2(va_[2], va_[3]);                \
    o_.z = pk2(vb_[0], vb_[1]); o_.w = pk2(vb_[2], vb_[3]);                \
    int kt_ = j * 4 + (acol >> 2);                                         \
    unsigned ib_ = swz((unsigned)(arow * 64 + (acol & 3) * 16));           \
    *(uint4*)(smem + kt_ * 4096 + ib_) = o_;                               \
  }                                                                        \
} while (0)

#define HALF_LOOP(KT0) do {                                                \
  const ushort* bp_ = Bmain + (size_t)(KT0) * 32768 + boff;                \
  bf16x8 bfA_[4], bfB_[4];                                                 \
  _Pragma("unroll")                                                        \
  for (int nf = 0; nf < 4; ++nf)                                           \
    bfA_[nf] = *(const bf16x8*)(bp_ + nf * 512);                           \
  _Pragma("unroll 1")                                                      \
  for (int kt = 0; kt < 32; kt += 2) {                                     \
    _Pragma("unroll")                                                      \
    for (int nf = 0; nf < 4; ++nf)                                         \
      bfB_[nf] = *(const bf16x8*)(bp_ + (size_t)(kt + 1) * 32768 + nf * 512); \
    {                                                                      \
      const char* ab_ = abase + (unsigned)(kt << 12);                      \
      bf16x8 af_[4];                                                       \
      _Pragma("unroll")                                                    \
      for (int mf = 0; mf < 4; ++mf)                                       \
        af_[mf] = *(const bf16x8*)(ab_ + mf * 1024);                       \
      __builtin_amdgcn_s_setprio(1);                                       \
      _Pragma("unroll")                                                    \
      for (int nf = 0; nf < 4; ++nf)                                       \
        _Pragma("unroll")                                                  \
        for (int mf = 0; mf < 4; ++mf)                                     \
          acc[mf][nf] = __builtin_amdgcn_mfma_f32_16x16x32_bf16(           \
              af_[mf], bfA_[nf], acc[mf][nf], 0, 0, 0);                    \
      __builtin_amdgcn_s_setprio(0);                                       \
    }                                                                      \
    _Pragma("unroll")                                                      \
    for (int nf = 0; nf < 4; ++nf)  /* kt=30: over-read -> Bk1, benign */  \
      bfA_[nf] = *(const bf16x8*)(bp_ + (size_t)(kt + 2) * 32768 + nf * 512); \
    {                                                                      \
      const char* ab_ = abase + (unsigned)((kt + 1) << 12);                \
      bf16x8 af_[4];                                                       \
      _Pragma("unroll")                                                    \
      for (int mf = 0; mf < 4; ++mf)                                       \
        af_[mf] = *(const bf16x8*)(ab_ + mf * 1024);                       \
      __builtin_amdgcn_s_setprio(1);                                       \
      _Pragma("unroll")                                                    \
      for (int nf = 0; nf < 4; ++nf)                                       \
        _Pragma("unroll")                                                  \
        for (int mf = 0; mf < 4; ++mf)                                     \
          acc[mf][nf] = __builtin_amdgcn_mfma_f32_16x16x32_bf16(           \
              af_[mf], bfB_[nf], acc[mf][nf], 0, 0, 0);                    \
      __builtin_amdgcn_s_setprio(0);                                       \
    }                                                                      \
  }                                                                        \
} while (0)

__global__ __launch_bounds__(1024) void main_kernel(
    const float* __restrict__ routed, const float* __restrict__ delta,
    const float* __restrict__ simrow, const ushort* __restrict__ Bmain,
    const float* __restrict__ tpart, const float* __restrict__ gamma,
    const float* __restrict__ beta, float* __restrict__ out_arg,
    ushort* __restrict__ argb) {
  extern __shared__ char smem[];
  // [0,131072): 32 per-kt A tiles x 4KB (one K-half, bf16, in-tile swizzle)
  // [131072,131328): ldsW
  // epilogue overlay: lnS [0,4096), lnQ [4096,8192)
  float* ldsW = (float*)(smem + 131072);
  float* lnS = (float*)smem;
  float* lnQ = (float*)(smem + 4096);

  int tid = threadIdx.x, l = tid & 63, wid = tid >> 6;   // wid 0..15
  int bx = blockIdx.x;                  // tokens bx*4 .. bx*4+3
  int lr = l & 15, lh = l >> 4;

  if (tid < 4) {                        // softmax over K=16 for token bx*4+tid
    int n = bx * 4 + tid;
    float sv[16], mx = -1e30f;
#pragma unroll
    for (int j = 0; j < 16; ++j) { sv[j] = simrow[n * 16 + j]; mx = fmaxf(mx, sv[j]); }
    float s = 0.f;
#pragma unroll
    for (int j = 0; j < 16; ++j) { sv[j] = expf(sv[j] - mx); s += sv[j]; }
    float inv = 1.0f / s;
#pragma unroll
    for (int j = 0; j < 16; ++j) ldsW[tid * 16 + j] = sv[j] * inv;
  }

  // staging geometry: thread covers row arow; per j, 8 f32 at elem
  // acol*8 + j*128 -> tile j*4+(acol>>2), in-tile byte (arow,(acol&3)*16)
  const int arow = tid >> 4;            // 0..63
  const int acol = tid & 15;            // 0..15

  // A-read addressing: tile kt, in-tile byte swz((mf*16+lr)*64 + lh*16);
  // swz's XOR key = bits 7,8 = lr bits 1,2 (mf-invariant; mf folds to +1024*mf)
  const unsigned aoff0 = swz((unsigned)(lr * 64 + lh * 16));
  const char* abase = smem + aoff0;

  // B per-lane offset (packed layout, unchanged)
  const size_t boff = (size_t)(wid >> 1) * 4096 + (size_t)(wid & 1) * 2048 +
                      (size_t)l * 8;

  f32x4 acc[4][4] = {};

  STAGE_HALF(routed);
  __syncthreads();
  HALF_LOOP(0);
  __syncthreads();                       // all reads of half 0 done
  STAGE_HALF(delta);
  __syncthreads();
  HALF_LOOP(32);
  __syncthreads();                       // reads done -> lnS/lnQ may overlay

  // ---- fused epilogue (green R16-R19; fast GELU, tpart NT) ----
  const float inv_d = 1.0f / 1024.0f;
  float gam[4], bet[4];
#pragma unroll
  for (int nf = 0; nf < 4; ++nf) {
    int c = wid * 64 + nf * 16 + lr;
    gam[nf] = gamma[c]; bet[nf] = beta[c];
  }
#pragma unroll
  for (int mf = 0; mf < 4; ++mf) {
    int tokrow = bx * 4 + mf;
    float s[4] = {0, 0, 0, 0}, q[4] = {0, 0, 0, 0};
#pragma unroll
    for (int nf = 0; nf < 4; ++nf) {
      float tp = __builtin_nontemporal_load(
          tpart + (size_t)tokrow * 1024 + wid * 64 + nf * 16 + lr);
#pragma unroll
      for (int j = 0; j < 4; ++j) {
        float h = acc[mf][nf][j] + tp;
        float u = h * (1.5957691f + 0.07135481f * h * h);
        float g = h / (1.0f + __expf(-u));
        acc[mf][nf][j] = g;
        s[j] += g; q[j] += g * g;
      }
    }
#pragma unroll
    for (int j = 0; j < 4; ++j) {
#pragma unroll
      for (int d = 1; d <= 8; d <<= 1) {
        s[j] += __shfl_xor(s[j], d, 64);
        q[j] += __shfl_xor(q[j], d, 64);
      }
    }
    if (lr == 0) {
#pragma unroll
      for (int j = 0; j < 4; ++j) {
        int row = mf * 16 + lh * 4 + j;
        lnS[row * 16 + wid] = s[j];
        lnQ[row * 16 + wid] = q[j];
      }
    }
  }
  __syncthreads();
#pragma unroll
  for (int mf = 0; mf < 4; ++mf) {
    float mu[4], rs[4], wk[4];
#pragma unroll
    for (int j = 0; j < 4; ++j) {
      int row = mf * 16 + lh * 4 + j;
      float S = 0.f, Q = 0.f;
#pragma unroll
      for (int w4 = 0; w4 < 4; ++w4) {
        f32x4 vs = *(const f32x4*)&lnS[row * 16 + w4 * 4];
        f32x4 vq = *(const f32x4*)&lnQ[row * 16 + w4 * 4];
        S += vs[0] + vs[1] + vs[2] + vs[3];
        Q += vq[0] + vq[1] + vq[2] + vq[3];
      }
      float m_ = S * inv_d;
      mu[j] = m_;
      rs[j] = rsqrtf(Q * inv_d - m_ * m_ + 1e-5f);
      wk[j] = ldsW[row];
    }
#pragma unroll
    for (int nf = 0; nf < 4; ++nf) {
      float ws = 0.f;
#pragma unroll
      for (int j = 0; j < 4; ++j) {
        float y = (acc[mf][nf][j] - mu[j]) * rs[j] * gam[nf] + bet[nf];
        ws += wk[j] * y;
      }
      ws += __shfl_xor(ws, 16, 64);
      ws += __shfl_xor(ws, 32, 64);
      if (lh == 0) {
        size_t oidx = (size_t)(bx * 4 + mf) * 1024 + wid * 64 + nf * 16 + lr;
        __builtin_nontemporal_store(ws, &out_arg[oidx]);   // never re-read
        argb[oidx] = f2bf(ws);                             // re-read 8x: cached
      }
    }
  }
}

// ---------------------------------------------------------------------------
extern "C" void kernel_launch(void* const* d_in, const int* in_sizes, int n_in,
                              void* d_out, int out_size, void* d_ws, size_t ws_size,
                              hipStream_t stream) {
  const float* token  = (const float*)d_in[0];
  const float* routed = (const float*)d_in[1];
  const float* simrow = (const float*)d_in[2];
  const float* delta  = (const float*)d_in[3];
  const float* Wl     = (const float*)d_in[4];
  const float* bl     = (const float*)d_in[5];
  const float* gamma  = (const float*)d_in[6];
  const float* beta   = (const float*)d_in[7];
  const float* Wg     = (const float*)d_in[8];
  const float* bg     = (const float*)d_in[9];

  char* ws = (char*)d_ws;
  ushort* Bmain  = (ushort*)(ws);                        // 4 MB
  ushort* Bk1    = (ushort*)(ws + (4u << 20));           // 2 MB
  ushort* Bgate  = (ushort*)(ws + (6u << 20));           // 4 MB
  float*  tpart  = (float*)(ws + (10u << 20));           // 16 MB
  ushort* tokenb = (ushort*)(ws + (26u << 20));          // 8 MB
  ushort* argb   = (ushort*)(ws + (34u << 20));          // 8 MB (total 42 MB)

  float* out_arg  = (float*)d_out;
  float* out_gate = out_arg + (size_t)4096 * 1024;

  const int SMEM = 131328;   // 32 A tiles 128K | ldsW 256B
  hipFuncSetAttribute(reinterpret_cast<const void*>(main_kernel),
                      hipFuncAttributeMaxDynamicSharedMemorySize, SMEM);

  prep_kernel<<<1536, 256, 0, stream>>>(Wl, Wg, token, Bmain, Bk1, Bgate, tokenb);
  gemm_small_b<32, 32, 0><<<dim3(64, 8), 256, 0, stream>>>(
      tokenb, tokenb, Bk1, bl, tpart);
  main_kernel<<<1024, 1024, SMEM, stream>>>(
      routed, delta, simrow, Bmain, tpart, gamma, beta, out_arg, argb);
  gemm_small_b<64, 32, 1><<<dim3(64, 8), 256, 0, stream>>>(
      tokenb, argb, Bgate, bg, out_gate);
}